// Round 1
// baseline (49737.061 us; speedup 1.0000x reference)
//
#include <hip/hip_runtime.h>
#include <hip/hip_bf16.h>
#include <math.h>

// Problem constants (gpt2-small + state plugin)
#define L_LAYERS 12
#define D_MODEL 768
#define H_HEADS 12
#define HD 64
#define NTOK 60
#define DST 128
#define BATCH 8
#define SEQ 1024
#define NT (BATCH * SEQ)      // 8192 rows
#define INJECT_L 8

// ---------------------------------------------------------------------------
// Scan: s_{t+1} = mul[ids_t, s_t], pre-states out. 8 independent chains.
// ---------------------------------------------------------------------------
__global__ __launch_bounds__(64) void scan_kernel(const int* __restrict__ ids,
                                                  const int* __restrict__ mul,
                                                  int* __restrict__ pre) {
    __shared__ int smul[NTOK * NTOK];
    for (int i = threadIdx.x; i < NTOK * NTOK; i += 64) smul[i] = mul[i];
    __syncthreads();
    int b = threadIdx.x;
    if (b < BATCH) {
        int st = 0;  // ID_ID
        const int* idr = ids + b * SEQ;
        int* pr = pre + b * SEQ;
        for (int t = 0; t < SEQ; t++) {
            pr[t] = st;
            st = smul[idr[t] * NTOK + st];
        }
    }
}

// ---------------------------------------------------------------------------
// Embed: s = state_emb[pre] @ sp_w + sp_b ;  h = tok_emb[ids] + s + wpe[t]
// one block per row
// ---------------------------------------------------------------------------
__global__ __launch_bounds__(256) void embed_kernel(const int* __restrict__ ids,
                                                    const int* __restrict__ pre,
                                                    const float* __restrict__ tok_emb,
                                                    const float* __restrict__ state_emb,
                                                    const float* __restrict__ sp_w,
                                                    const float* __restrict__ sp_b,
                                                    const float* __restrict__ wpe,
                                                    float* __restrict__ s,
                                                    float* __restrict__ h) {
    int n = blockIdx.x;          // b*SEQ + t
    int t = n & (SEQ - 1);
    int id = ids[n];
    int ps = pre[n];
    __shared__ float se[DST];
    if (threadIdx.x < DST) se[threadIdx.x] = state_emb[ps * DST + threadIdx.x];
    __syncthreads();
    for (int d = threadIdx.x; d < D_MODEL; d += 256) {
        float acc = sp_b[d];
        #pragma unroll 8
        for (int k = 0; k < DST; k++) acc += se[k] * sp_w[k * D_MODEL + d];
        size_t o = (size_t)n * D_MODEL + d;
        s[o] = acc;
        h[o] = tok_emb[id * D_MODEL + d] + acc + wpe[t * D_MODEL + d];
    }
}

// ---------------------------------------------------------------------------
// LayerNorm over D=768. One block per row; strides allow lnf-on-last-token.
// ---------------------------------------------------------------------------
__global__ __launch_bounds__(256) void ln_kernel(const float* __restrict__ x,
                                                 const float* __restrict__ g,
                                                 const float* __restrict__ bta,
                                                 float* __restrict__ out,
                                                 long in_stride, long out_stride) {
    long row = blockIdx.x;
    const float* xr = x + row * in_stride;
    int tid = threadIdx.x;
    float v0 = xr[tid], v1 = xr[tid + 256], v2 = xr[tid + 512];
    float sum = v0 + v1 + v2;
    float sq = v0 * v0 + v1 * v1 + v2 * v2;
    for (int off = 32; off; off >>= 1) {
        sum += __shfl_xor(sum, off);
        sq += __shfl_xor(sq, off);
    }
    __shared__ float red[8];
    int wid = tid >> 6;
    if ((tid & 63) == 0) { red[wid] = sum; red[4 + wid] = sq; }
    __syncthreads();
    sum = red[0] + red[1] + red[2] + red[3];
    sq = red[4] + red[5] + red[6] + red[7];
    float mean = sum * (1.0f / D_MODEL);
    float var = sq * (1.0f / D_MODEL) - mean * mean;
    float r = rsqrtf(var + 1e-5f);
    float* orow = out + row * out_stride;
    orow[tid] = (v0 - mean) * r * g[tid] + bta[tid];
    orow[tid + 256] = (v1 - mean) * r * g[tid + 256] + bta[tid + 256];
    orow[tid + 512] = (v2 - mean) * r * g[tid + 512] + bta[tid + 512];
}

// ---------------------------------------------------------------------------
// Generic fp32 GEMM: C = act(residual + A[M,K] @ W[K,N] + bias[N])
// 64x64 tile, K-step 16, 256 threads, 4x4 per thread.
// act: 0 = none, 1 = tanh-GELU
// ---------------------------------------------------------------------------
__device__ __forceinline__ float gelu_tanh(float x) {
    float c = 0.7978845608028654f * (x + 0.044715f * x * x * x);
    return 0.5f * x * (1.0f + tanhf(c));
}

__global__ __launch_bounds__(256) void gemm_kernel(const float* __restrict__ A,
                                                   const float* __restrict__ W,
                                                   const float* __restrict__ bias,
                                                   const float* __restrict__ residual,
                                                   float* __restrict__ C,
                                                   int M, int K, int N, int act) {
    __shared__ float As[16][64];
    __shared__ float Bs[16][64];
    int bm = blockIdx.x, bn = blockIdx.y;
    int tid = threadIdx.x;
    int tm = (tid / 16) * 4;
    int tn = (tid % 16) * 4;
    int m0 = bm * 64, n0 = bn * 64;
    int la_k = tid % 16, la_m = tid / 16;   // A: 64 rows x 16 cols
    int lb_n = tid % 64, lb_k = tid / 64;   // W: 16 rows x 64 cols
    float acc[4][4] = {};
    for (int k0 = 0; k0 < K; k0 += 16) {
        #pragma unroll
        for (int i = 0; i < 4; i++)
            As[la_k][la_m + 16 * i] = A[(size_t)(m0 + la_m + 16 * i) * K + k0 + la_k];
        #pragma unroll
        for (int i = 0; i < 4; i++)
            Bs[lb_k + 4 * i][lb_n] = W[(size_t)(k0 + lb_k + 4 * i) * N + n0 + lb_n];
        __syncthreads();
        #pragma unroll
        for (int k = 0; k < 16; k++) {
            float a0 = As[k][tm], a1 = As[k][tm + 1], a2 = As[k][tm + 2], a3 = As[k][tm + 3];
            float b0 = Bs[k][tn], b1 = Bs[k][tn + 1], b2 = Bs[k][tn + 2], b3 = Bs[k][tn + 3];
            acc[0][0] += a0 * b0; acc[0][1] += a0 * b1; acc[0][2] += a0 * b2; acc[0][3] += a0 * b3;
            acc[1][0] += a1 * b0; acc[1][1] += a1 * b1; acc[1][2] += a1 * b2; acc[1][3] += a1 * b3;
            acc[2][0] += a2 * b0; acc[2][1] += a2 * b1; acc[2][2] += a2 * b2; acc[2][3] += a2 * b3;
            acc[3][0] += a3 * b0; acc[3][1] += a3 * b1; acc[3][2] += a3 * b2; acc[3][3] += a3 * b3;
        }
        __syncthreads();
    }
    #pragma unroll
    for (int i = 0; i < 4; i++) {
        #pragma unroll
        for (int j = 0; j < 4; j++) {
            size_t idx = (size_t)(m0 + tm + i) * N + n0 + tn + j;
            float v = acc[i][j] + bias[n0 + tn + j];
            if (residual) v += residual[idx];
            if (act == 1) v = gelu_tanh(v);
            C[idx] = v;
        }
    }
}

// ---------------------------------------------------------------------------
// Attention: one wave (64 threads) per (b, h, t) query row. Scores in LDS.
// qkv layout: [B*T, 3*D]; q at +h*64, k at +768+h*64, v at +1536+h*64
// ---------------------------------------------------------------------------
__global__ __launch_bounds__(64) void attn_kernel(const float* __restrict__ qkv,
                                                  float* __restrict__ o) {
    int t = blockIdx.x, hh = blockIdx.y, b = blockIdx.z;
    int lane = threadIdx.x;
    __shared__ float sc[SEQ];
    __shared__ float qs[HD];
    const size_t rowstride = 3 * D_MODEL;
    const float* qrow = qkv + ((size_t)(b * SEQ + t)) * rowstride + hh * HD;
    qs[lane] = qrow[lane];
    __syncthreads();
    const float4* q4 = (const float4*)qs;
    float lmax = -1e30f;
    for (int j = lane; j <= t; j += 64) {
        const float4* k4 = (const float4*)(qkv + ((size_t)(b * SEQ + j)) * rowstride + D_MODEL + hh * HD);
        float dot = 0.0f;
        #pragma unroll
        for (int kk = 0; kk < HD / 4; kk++) {
            float4 kv = k4[kk];
            float4 qv = q4[kk];
            dot += qv.x * kv.x + qv.y * kv.y + qv.z * kv.z + qv.w * kv.w;
        }
        dot *= 0.125f;   // 1/sqrt(64)
        sc[j] = dot;
        lmax = fmaxf(lmax, dot);
    }
    for (int off = 32; off; off >>= 1) lmax = fmaxf(lmax, __shfl_xor(lmax, off));
    float lsum = 0.0f;
    for (int j = lane; j <= t; j += 64) {
        float p = __expf(sc[j] - lmax);
        sc[j] = p;
        lsum += p;
    }
    for (int off = 32; off; off >>= 1) lsum += __shfl_xor(lsum, off);
    float inv = 1.0f / lsum;
    __syncthreads();
    // o[d], d = lane; coalesced v reads, sc broadcast
    float acc = 0.0f;
    const float* vbase = qkv + (size_t)b * SEQ * rowstride + 2 * D_MODEL + hh * HD + lane;
    for (int j = 0; j <= t; j++) {
        acc += sc[j] * vbase[(size_t)j * rowstride];
    }
    o[((size_t)(b * SEQ + t)) * D_MODEL + hh * HD + lane] = acc * inv;
}

// ---------------------------------------------------------------------------
// Gate fusion (layer 8): h += sigmoid(z) * dv
// ---------------------------------------------------------------------------
__global__ __launch_bounds__(256) void gate_kernel(float* __restrict__ h,
                                                   const float* __restrict__ z,
                                                   const float* __restrict__ dv,
                                                   size_t total) {
    size_t i = (size_t)blockIdx.x * blockDim.x + threadIdx.x;
    size_t stride = (size_t)gridDim.x * blockDim.x;
    for (; i < total; i += stride) {
        float g = 1.0f / (1.0f + __expf(-z[i]));
        h[i] += g * dv[i];
    }
}

// ---------------------------------------------------------------------------
// Head: logits[b] = hn[b] @ head_w + head_b   (8 x 768 x 60)
// ---------------------------------------------------------------------------
__global__ __launch_bounds__(64) void head_kernel(const float* __restrict__ hn,
                                                  const float* __restrict__ head_w,
                                                  const float* __restrict__ head_b,
                                                  float* __restrict__ out) {
    int b = blockIdx.x;
    int n = threadIdx.x;
    if (n < NTOK) {
        float acc = head_b[n];
        const float* hr = hn + b * D_MODEL;
        for (int k = 0; k < D_MODEL; k++) acc += hr[k] * head_w[k * NTOK + n];
        out[b * NTOK + n] = acc;
    }
}

// ---------------------------------------------------------------------------
extern "C" void kernel_launch(void* const* d_in, const int* in_sizes, int n_in,
                              void* d_out, int out_size, void* d_ws, size_t ws_size,
                              hipStream_t stream) {
    (void)in_sizes; (void)n_in; (void)out_size; (void)ws_size;
    const int* input_ids = (const int*)d_in[0];
    const int* mul       = (const int*)d_in[1];
    const float* tok_emb = (const float*)d_in[2];
    const float* state_emb = (const float*)d_in[3];
    const float* sp_w = (const float*)d_in[4];
    const float* sp_b = (const float*)d_in[5];
    const float* wh_w = (const float*)d_in[6];
    const float* wh_b = (const float*)d_in[7];
    const float* ws_w = (const float*)d_in[8];
    const float* ws_b = (const float*)d_in[9];
    const float* wd_w = (const float*)d_in[10];
    const float* wd_b = (const float*)d_in[11];
    const float* head_w = (const float*)d_in[12];
    const float* head_b = (const float*)d_in[13];
    const float* wpe  = (const float*)d_in[14];
    const float* ln1_g = (const float*)d_in[15];
    const float* ln1_b = (const float*)d_in[16];
    const float* attn_w = (const float*)d_in[17];
    const float* attn_b = (const float*)d_in[18];
    const float* proj_w = (const float*)d_in[19];
    const float* proj_b = (const float*)d_in[20];
    const float* ln2_g = (const float*)d_in[21];
    const float* ln2_b = (const float*)d_in[22];
    const float* fc_w = (const float*)d_in[23];
    const float* fc_b = (const float*)d_in[24];
    const float* mproj_w = (const float*)d_in[25];
    const float* mproj_b = (const float*)d_in[26];
    const float* lnf_g = (const float*)d_in[27];
    const float* lnf_b = (const float*)d_in[28];
    float* out = (float*)d_out;

    // Workspace layout
    size_t off = 0;
    auto alloc = [&](size_t bytes) {
        void* p = (char*)d_ws + off;
        off += (bytes + 255) & ~(size_t)255;
        return p;
    };
    int* pre   = (int*)alloc((size_t)NT * 4);
    float* s   = (float*)alloc((size_t)NT * D_MODEL * 4);
    float* h   = (float*)alloc((size_t)NT * D_MODEL * 4);
    float* a   = (float*)alloc((size_t)NT * D_MODEL * 4);
    float* qkv = (float*)alloc((size_t)NT * 3 * D_MODEL * 4);
    float* u   = (float*)alloc((size_t)NT * 4 * D_MODEL * 4);
    float* hn  = (float*)alloc((size_t)BATCH * D_MODEL * 4);
    float* z   = u;                       // layer-8 reuse of u
    float* dv  = u + (size_t)NT * D_MODEL;

    scan_kernel<<<1, 64, 0, stream>>>(input_ids, mul, pre);
    embed_kernel<<<NT, 256, 0, stream>>>(input_ids, pre, tok_emb, state_emb,
                                         sp_w, sp_b, wpe, s, h);

    dim3 blk256(256);
    for (int l = 0; l < L_LAYERS; l++) {
        const float* lw_attn_w = attn_w + (size_t)l * D_MODEL * 3 * D_MODEL;
        const float* lw_attn_b = attn_b + (size_t)l * 3 * D_MODEL;
        const float* lw_proj_w = proj_w + (size_t)l * D_MODEL * D_MODEL;
        const float* lw_proj_b = proj_b + (size_t)l * D_MODEL;
        const float* lw_fc_w   = fc_w + (size_t)l * D_MODEL * 4 * D_MODEL;
        const float* lw_fc_b   = fc_b + (size_t)l * 4 * D_MODEL;
        const float* lw_mp_w   = mproj_w + (size_t)l * 4 * D_MODEL * D_MODEL;
        const float* lw_mp_b   = mproj_b + (size_t)l * D_MODEL;

        ln_kernel<<<NT, blk256, 0, stream>>>(h, ln1_g + l * D_MODEL, ln1_b + l * D_MODEL,
                                             a, D_MODEL, D_MODEL);
        gemm_kernel<<<dim3(NT / 64, 3 * D_MODEL / 64), blk256, 0, stream>>>(
            a, lw_attn_w, lw_attn_b, nullptr, qkv, NT, D_MODEL, 3 * D_MODEL, 0);
        attn_kernel<<<dim3(SEQ, H_HEADS, BATCH), 64, 0, stream>>>(qkv, a);
        gemm_kernel<<<dim3(NT / 64, D_MODEL / 64), blk256, 0, stream>>>(
            a, lw_proj_w, lw_proj_b, h, h, NT, D_MODEL, D_MODEL, 0);
        ln_kernel<<<NT, blk256, 0, stream>>>(h, ln2_g + l * D_MODEL, ln2_b + l * D_MODEL,
                                             a, D_MODEL, D_MODEL);
        gemm_kernel<<<dim3(NT / 64, 4 * D_MODEL / 64), blk256, 0, stream>>>(
            a, lw_fc_w, lw_fc_b, nullptr, u, NT, D_MODEL, 4 * D_MODEL, 1);
        gemm_kernel<<<dim3(NT / 64, D_MODEL / 64), blk256, 0, stream>>>(
            u, lw_mp_w, lw_mp_b, h, h, NT, 4 * D_MODEL, D_MODEL, 0);

        if (l == INJECT_L) {
            gemm_kernel<<<dim3(NT / 64, D_MODEL / 64), blk256, 0, stream>>>(
                h, wh_w, wh_b, nullptr, z, NT, D_MODEL, D_MODEL, 0);
            gemm_kernel<<<dim3(NT / 64, D_MODEL / 64), blk256, 0, stream>>>(
                s, ws_w, ws_b, z, z, NT, D_MODEL, D_MODEL, 0);
            gemm_kernel<<<dim3(NT / 64, D_MODEL / 64), blk256, 0, stream>>>(
                s, wd_w, wd_b, nullptr, dv, NT, D_MODEL, D_MODEL, 0);
            gate_kernel<<<dim3(2048), blk256, 0, stream>>>(h, z, dv, (size_t)NT * D_MODEL);
        }
    }

    // lnf on the 8 last-token rows only, then head
    ln_kernel<<<BATCH, blk256, 0, stream>>>(h + (size_t)(SEQ - 1) * D_MODEL,
                                            lnf_g, lnf_b, hn,
                                            (long)SEQ * D_MODEL, D_MODEL);
    head_kernel<<<BATCH, 64, 0, stream>>>(hn, head_w, head_b, out);
}

// Round 2
// 5312.227 us; speedup vs baseline: 9.3628x; 9.3628x over previous
//
#include <hip/hip_runtime.h>
#include <hip/hip_bf16.h>
#include <math.h>

// Problem constants (gpt2-small + state plugin)
#define L_LAYERS 12
#define D_MODEL 768
#define H_HEADS 12
#define HD 64
#define NTOK 60
#define DST 128
#define BATCH 8
#define SEQ 1024
#define NT (BATCH * SEQ)      // 8192 rows
#define INJECT_L 8

typedef short bf16x8 __attribute__((ext_vector_type(8)));
typedef float f32x4 __attribute__((ext_vector_type(4)));

__device__ __forceinline__ unsigned short f2bf(float f) {
    unsigned int u = __float_as_uint(f);
    u = (u + 0x7FFF + ((u >> 16) & 1)) >> 16;   // RNE
    return (unsigned short)u;
}

__device__ __forceinline__ float gelu_tanh(float x) {
    float c = 0.7978845608028654f * (x + 0.044715f * x * x * x);
    return 0.5f * x * (1.0f + tanhf(c));
}

// async 16B global->LDS (dest = wave-uniform base + lane*16)
__device__ __forceinline__ void async_copy16(void* lds, const void* gmem) {
    __builtin_amdgcn_global_load_lds(
        (const __attribute__((address_space(1))) unsigned int*)gmem,
        (__attribute__((address_space(3))) unsigned int*)lds,
        16, 0, 0);
}

// ---------------------------------------------------------------------------
// Scan: s_{t+1} = mul[ids_t, s_t]
// ---------------------------------------------------------------------------
__global__ __launch_bounds__(64) void scan_kernel(const int* __restrict__ ids,
                                                  const int* __restrict__ mul,
                                                  int* __restrict__ pre) {
    __shared__ int smul[NTOK * NTOK];
    for (int i = threadIdx.x; i < NTOK * NTOK; i += 64) smul[i] = mul[i];
    __syncthreads();
    int b = threadIdx.x;
    if (b < BATCH) {
        int st = 0;
        const int* idr = ids + b * SEQ;
        int* pr = pre + b * SEQ;
        for (int t = 0; t < SEQ; t++) {
            pr[t] = st;
            st = smul[idr[t] * NTOK + st];
        }
    }
}

// ---------------------------------------------------------------------------
// Embed: s = state_emb[pre] @ sp_w + sp_b (bf16 out for inject GEMMs);
//        h = tok_emb[ids] + s + wpe[t]  (fp32)
// ---------------------------------------------------------------------------
__global__ __launch_bounds__(256) void embed_kernel(const int* __restrict__ ids,
                                                    const int* __restrict__ pre,
                                                    const float* __restrict__ tok_emb,
                                                    const float* __restrict__ state_emb,
                                                    const float* __restrict__ sp_w,
                                                    const float* __restrict__ sp_b,
                                                    const float* __restrict__ wpe,
                                                    unsigned short* __restrict__ s_bf,
                                                    float* __restrict__ h) {
    int n = blockIdx.x;
    int t = n & (SEQ - 1);
    int id = ids[n];
    int ps = pre[n];
    __shared__ float se[DST];
    if (threadIdx.x < DST) se[threadIdx.x] = state_emb[ps * DST + threadIdx.x];
    __syncthreads();
    for (int d = threadIdx.x; d < D_MODEL; d += 256) {
        float acc = sp_b[d];
        #pragma unroll 8
        for (int k = 0; k < DST; k++) acc += se[k] * sp_w[k * D_MODEL + d];
        size_t o = (size_t)n * D_MODEL + d;
        s_bf[o] = f2bf(acc);
        h[o] = tok_emb[id * D_MODEL + d] + acc + wpe[t * D_MODEL + d];
    }
}

// ---------------------------------------------------------------------------
// LayerNorm fp32 -> fp32 (for lnf) and fp32 -> bf16 (GEMM A-inputs)
// ---------------------------------------------------------------------------
__device__ __forceinline__ void ln_core(const float* xr, float& mean, float& rstd,
                                        float& v0, float& v1, float& v2, int tid) {
    v0 = xr[tid]; v1 = xr[tid + 256]; v2 = xr[tid + 512];
    float sum = v0 + v1 + v2;
    float sq = v0 * v0 + v1 * v1 + v2 * v2;
    for (int off = 32; off; off >>= 1) {
        sum += __shfl_xor(sum, off);
        sq += __shfl_xor(sq, off);
    }
    __shared__ float red[8];
    int wid = tid >> 6;
    if ((tid & 63) == 0) { red[wid] = sum; red[4 + wid] = sq; }
    __syncthreads();
    sum = red[0] + red[1] + red[2] + red[3];
    sq = red[4] + red[5] + red[6] + red[7];
    mean = sum * (1.0f / D_MODEL);
    float var = sq * (1.0f / D_MODEL) - mean * mean;
    rstd = rsqrtf(var + 1e-5f);
}

__global__ __launch_bounds__(256) void ln_f32_kernel(const float* __restrict__ x,
                                                     const float* __restrict__ g,
                                                     const float* __restrict__ bta,
                                                     float* __restrict__ out,
                                                     long in_stride, long out_stride) {
    long row = blockIdx.x;
    const float* xr = x + row * in_stride;
    int tid = threadIdx.x;
    float mean, r, v0, v1, v2;
    ln_core(xr, mean, r, v0, v1, v2, tid);
    float* orow = out + row * out_stride;
    orow[tid] = (v0 - mean) * r * g[tid] + bta[tid];
    orow[tid + 256] = (v1 - mean) * r * g[tid + 256] + bta[tid + 256];
    orow[tid + 512] = (v2 - mean) * r * g[tid + 512] + bta[tid + 512];
}

__global__ __launch_bounds__(256) void ln_bf16_kernel(const float* __restrict__ x,
                                                      const float* __restrict__ g,
                                                      const float* __restrict__ bta,
                                                      unsigned short* __restrict__ out) {
    long row = blockIdx.x;
    const float* xr = x + row * (long)D_MODEL;
    int tid = threadIdx.x;
    float mean, r, v0, v1, v2;
    ln_core(xr, mean, r, v0, v1, v2, tid);
    unsigned short* orow = out + row * (long)D_MODEL;
    orow[tid] = f2bf((v0 - mean) * r * g[tid] + bta[tid]);
    orow[tid + 256] = f2bf((v1 - mean) * r * g[tid + 256] + bta[tid + 256]);
    orow[tid + 512] = f2bf((v2 - mean) * r * g[tid + 512] + bta[tid + 512]);
}

// ---------------------------------------------------------------------------
// Weight convert+transpose: src fp32 [R][C] -> dst bf16 [C][R]
// ---------------------------------------------------------------------------
__global__ __launch_bounds__(256) void wconv_t(const float* __restrict__ src,
                                               unsigned short* __restrict__ dst,
                                               int R, int C) {
    __shared__ float tile[32][33];
    int r0 = blockIdx.x * 32, c0 = blockIdx.y * 32;
    int tc = threadIdx.x, tr = threadIdx.y;   // (32,8)
    #pragma unroll
    for (int i = 0; i < 32; i += 8)
        tile[tr + i][tc] = src[(size_t)(r0 + tr + i) * C + c0 + tc];
    __syncthreads();
    #pragma unroll
    for (int i = 0; i < 32; i += 8)
        dst[(size_t)(c0 + tr + i) * R + r0 + tc] = f2bf(tile[tc][tr + i]);
}

// ---------------------------------------------------------------------------
// bf16 MFMA GEMM: C = epilogue(A[M,K] @ Wt[N,K]^T + bias)
// 128x128 tile, BK=32, 256 threads (4 waves, 2x2 of 64x64), m97-style staging.
// ---------------------------------------------------------------------------
#define FLAG_OUTBF16 1
#define FLAG_GELU 2
#define FLAG_RESID 4
#define FLAG_MIRROR 8

__global__ __launch_bounds__(256) void mfma_gemm(const unsigned short* __restrict__ A,
                                                 const unsigned short* __restrict__ Wt,
                                                 const float* __restrict__ bias,
                                                 const float* __restrict__ residual,
                                                 float* __restrict__ Cf,
                                                 unsigned short* __restrict__ Cb,
                                                 unsigned short* __restrict__ Cmir,
                                                 int M, int K, int N, int flags) {
    __shared__ unsigned short As[128 * 32];
    __shared__ unsigned short Bs[128 * 32];
    int tid = threadIdx.x;
    int wave = tid >> 6, lane = tid & 63;
    int quad = lane >> 4, l16 = lane & 15;
    int m0 = blockIdx.x * 128, n0 = blockIdx.y * 128;
    int wm = (wave & 1) * 64, wn = (wave >> 1) * 64;
    f32x4 acc[4][4] = {};

    int chunk0 = wave * 64 + lane;   // lane's chunk id (i*256 + chunk0)
    for (int k0 = 0; k0 < K; k0 += 32) {
        #pragma unroll
        for (int i = 0; i < 2; i++) {
            int chunk = i * 256 + chunk0;
            int r = chunk >> 2, cc = chunk & 3;
            // wave-uniform LDS base: chunk index (i*256 + wave*64), 8 ushorts/chunk
            async_copy16(&As[(i * 256 + wave * 64) * 8],
                         A + (size_t)(m0 + r) * K + k0 + cc * 8);
            async_copy16(&Bs[(i * 256 + wave * 64) * 8],
                         Wt + (size_t)(n0 + r) * K + k0 + cc * 8);
        }
        __syncthreads();
        bf16x8 af[4], bfr[4];
        #pragma unroll
        for (int mi = 0; mi < 4; mi++)
            af[mi] = *(const bf16x8*)&As[(wm + mi * 16 + l16) * 32 + quad * 8];
        #pragma unroll
        for (int ni = 0; ni < 4; ni++)
            bfr[ni] = *(const bf16x8*)&Bs[(wn + ni * 16 + l16) * 32 + quad * 8];
        #pragma unroll
        for (int mi = 0; mi < 4; mi++)
            #pragma unroll
            for (int ni = 0; ni < 4; ni++)
                acc[mi][ni] = __builtin_amdgcn_mfma_f32_16x16x32_bf16(
                    af[mi], bfr[ni], acc[mi][ni], 0, 0, 0);
        __syncthreads();
    }
    #pragma unroll
    for (int mi = 0; mi < 4; mi++) {
        #pragma unroll
        for (int ni = 0; ni < 4; ni++) {
            int col = n0 + wn + ni * 16 + l16;
            float bv = bias[col];
            #pragma unroll
            for (int r = 0; r < 4; r++) {
                int row = m0 + wm + mi * 16 + quad * 4 + r;
                size_t idx = (size_t)row * N + col;
                float v = acc[mi][ni][r] + bv;
                if (flags & FLAG_RESID) v += residual[idx];
                if (flags & FLAG_GELU) v = gelu_tanh(v);
                if (flags & FLAG_OUTBF16) Cb[idx] = f2bf(v);
                else Cf[idx] = v;
                if (flags & FLAG_MIRROR) Cmir[idx] = f2bf(v);
            }
        }
    }
}

// ---------------------------------------------------------------------------
// Flash attention, bf16 MFMA. Block = 4 waves; wave w owns q-rows
// [q0+w*16, q0+w*16+16). Shared K/V^T tiles of 64 keys. Online softmax.
// qkv bf16 [NT][2304]; out bf16 [NT][768].
// ---------------------------------------------------------------------------
__global__ __launch_bounds__(256) void attn_mfma(const unsigned short* __restrict__ qkv,
                                                 unsigned short* __restrict__ o) {
    int qt = blockIdx.x, hh = blockIdx.y, b = blockIdx.z;
    int tid = threadIdx.x, wave = tid >> 6, lane = tid & 63;
    int quad = lane >> 4, l16 = lane & 15;
    __shared__ unsigned short Qs[64][72];   // [qrow][hd], pad 72 (16B-aligned rows)
    __shared__ unsigned short Ks[64][72];   // [key][hd]
    __shared__ unsigned short Vt[64][72];   // [hd][key]
    __shared__ unsigned short Ps[4][16][72];// per-wave P in A-layout feed
    const size_t rstride = 3 * D_MODEL;
    int q0 = qt * 64;

    // stage Q (64 rows x 64 hd)
    {
        size_t qbase = ((size_t)(b * SEQ + q0)) * rstride + hh * HD;
        #pragma unroll
        for (int i = 0; i < 2; i++) {
            int chunk = i * 256 + tid;
            int r = chunk >> 3, cc = chunk & 7;
            *(uint4*)&Qs[r][cc * 8] =
                *(const uint4*)(qkv + qbase + (size_t)r * rstride + cc * 8);
        }
    }

    float m_r[4] = {-1e30f, -1e30f, -1e30f, -1e30f};
    float l_r[4] = {0.f, 0.f, 0.f, 0.f};
    f32x4 oacc[4] = {};

    for (int kt = 0; kt <= qt; kt++) {
        int kb = kt * 64;
        __syncthreads();   // previous iter's LDS reads done (also covers Q staging)
        size_t kbase = ((size_t)(b * SEQ + kb)) * rstride + D_MODEL + hh * HD;
        size_t vbase = ((size_t)(b * SEQ + kb)) * rstride + 2 * D_MODEL + hh * HD;
        #pragma unroll
        for (int i = 0; i < 2; i++) {
            int chunk = i * 256 + tid;
            int r = chunk >> 3, cc = chunk & 7;
            *(uint4*)&Ks[r][cc * 8] =
                *(const uint4*)(qkv + kbase + (size_t)r * rstride + cc * 8);
        }
        {
            int hd = tid & 63;
            int kk0 = (tid >> 6) * 16;
            #pragma unroll
            for (int j = 0; j < 16; j++) {
                int key = kk0 + j;
                Vt[hd][key] = qkv[vbase + (size_t)key * rstride + hd];
            }
        }
        __syncthreads();

        // S = Q K^T  (16 q-rows x 64 keys per wave)
        f32x4 sacc[4] = {};
        bf16x8 qf0 = *(const bf16x8*)&Qs[wave * 16 + l16][quad * 8];
        bf16x8 qf1 = *(const bf16x8*)&Qs[wave * 16 + l16][32 + quad * 8];
        #pragma unroll
        for (int ni = 0; ni < 4; ni++) {
            bf16x8 kf0 = *(const bf16x8*)&Ks[ni * 16 + l16][quad * 8];
            bf16x8 kf1 = *(const bf16x8*)&Ks[ni * 16 + l16][32 + quad * 8];
            sacc[ni] = __builtin_amdgcn_mfma_f32_16x16x32_bf16(qf0, kf0, sacc[ni], 0, 0, 0);
            sacc[ni] = __builtin_amdgcn_mfma_f32_16x16x32_bf16(qf1, kf1, sacc[ni], 0, 0, 0);
        }

        // online softmax
        bool diag = (kt == qt);
        const float scale = 0.125f;
        #pragma unroll
        for (int r = 0; r < 4; r++) {
            int qrow_loc = wave * 16 + quad * 4 + r;
            float mx = m_r[r];
            #pragma unroll
            for (int ni = 0; ni < 4; ni++) {
                float sv = sacc[ni][r] * scale;
                if (diag && (ni * 16 + l16 > qrow_loc)) sv = -1e30f;
                sacc[ni][r] = sv;
                mx = fmaxf(mx, sv);
            }
            for (int off = 8; off; off >>= 1) mx = fmaxf(mx, __shfl_xor(mx, off));
            float alpha = __expf(m_r[r] - mx);
            m_r[r] = mx;
            float ls = 0.f;
            #pragma unroll
            for (int ni = 0; ni < 4; ni++) {
                float p = __expf(sacc[ni][r] - mx);
                sacc[ni][r] = p;
                ls += p;
            }
            for (int off = 8; off; off >>= 1) ls += __shfl_xor(ls, off);
            l_r[r] = l_r[r] * alpha + ls;
            #pragma unroll
            for (int ni = 0; ni < 4; ni++) oacc[ni][r] *= alpha;
        }

        // P -> LDS (C-layout write), reread as A-layout fragments
        #pragma unroll
        for (int ni = 0; ni < 4; ni++)
            #pragma unroll
            for (int r = 0; r < 4; r++)
                Ps[wave][quad * 4 + r][ni * 16 + l16] = f2bf(sacc[ni][r]);
        asm volatile("s_waitcnt lgkmcnt(0)" ::: "memory");

        bf16x8 pf0 = *(const bf16x8*)&Ps[wave][l16][quad * 8];
        bf16x8 pf1 = *(const bf16x8*)&Ps[wave][l16][32 + quad * 8];
        #pragma unroll
        for (int ni = 0; ni < 4; ni++) {
            bf16x8 vf0 = *(const bf16x8*)&Vt[ni * 16 + l16][quad * 8];
            bf16x8 vf1 = *(const bf16x8*)&Vt[ni * 16 + l16][32 + quad * 8];
            oacc[ni] = __builtin_amdgcn_mfma_f32_16x16x32_bf16(pf0, vf0, oacc[ni], 0, 0, 0);
            oacc[ni] = __builtin_amdgcn_mfma_f32_16x16x32_bf16(pf1, vf1, oacc[ni], 0, 0, 0);
        }
    }

    #pragma unroll
    for (int ni = 0; ni < 4; ni++) {
        #pragma unroll
        for (int r = 0; r < 4; r++) {
            float inv = 1.0f / l_r[r];
            int row = q0 + wave * 16 + quad * 4 + r;
            o[((size_t)(b * SEQ + row)) * D_MODEL + hh * HD + ni * 16 + l16] =
                f2bf(oacc[ni][r] * inv);
        }
    }
}

// ---------------------------------------------------------------------------
// Gate fusion (layer 8): h += sigmoid(z) * dv
// ---------------------------------------------------------------------------
__global__ __launch_bounds__(256) void gate_kernel(float* __restrict__ h,
                                                   const float* __restrict__ z,
                                                   const float* __restrict__ dv,
                                                   size_t total) {
    size_t i = (size_t)blockIdx.x * blockDim.x + threadIdx.x;
    size_t stride = (size_t)gridDim.x * blockDim.x;
    for (; i < total; i += stride) {
        float g = 1.0f / (1.0f + __expf(-z[i]));
        h[i] += g * dv[i];
    }
}

// ---------------------------------------------------------------------------
// Head: logits[b] = hn[b] @ head_w + head_b   (8 x 768 x 60)
// ---------------------------------------------------------------------------
__global__ __launch_bounds__(64) void head_kernel(const float* __restrict__ hn,
                                                  const float* __restrict__ head_w,
                                                  const float* __restrict__ head_b,
                                                  float* __restrict__ out) {
    int b = blockIdx.x;
    int n = threadIdx.x;
    if (n < NTOK) {
        float acc = head_b[n];
        const float* hr = hn + b * D_MODEL;
        for (int k = 0; k < D_MODEL; k++) acc += hr[k] * head_w[k * NTOK + n];
        out[b * NTOK + n] = acc;
    }
}

// ---------------------------------------------------------------------------
extern "C" void kernel_launch(void* const* d_in, const int* in_sizes, int n_in,
                              void* d_out, int out_size, void* d_ws, size_t ws_size,
                              hipStream_t stream) {
    (void)in_sizes; (void)n_in; (void)out_size; (void)ws_size;
    const int* input_ids = (const int*)d_in[0];
    const int* mul       = (const int*)d_in[1];
    const float* tok_emb = (const float*)d_in[2];
    const float* state_emb = (const float*)d_in[3];
    const float* sp_w = (const float*)d_in[4];
    const float* sp_b = (const float*)d_in[5];
    const float* wh_w = (const float*)d_in[6];
    const float* wh_b = (const float*)d_in[7];
    const float* ws_w = (const float*)d_in[8];
    const float* ws_b = (const float*)d_in[9];
    const float* wd_w = (const float*)d_in[10];
    const float* wd_b = (const float*)d_in[11];
    const float* head_w = (const float*)d_in[12];
    const float* head_b = (const float*)d_in[13];
    const float* wpe  = (const float*)d_in[14];
    const float* ln1_g = (const float*)d_in[15];
    const float* ln1_b = (const float*)d_in[16];
    const float* attn_w = (const float*)d_in[17];
    const float* attn_b = (const float*)d_in[18];
    const float* proj_w = (const float*)d_in[19];
    const float* proj_b = (const float*)d_in[20];
    const float* ln2_g = (const float*)d_in[21];
    const float* ln2_b = (const float*)d_in[22];
    const float* fc_w = (const float*)d_in[23];
    const float* fc_b = (const float*)d_in[24];
    const float* mproj_w = (const float*)d_in[25];
    const float* mproj_b = (const float*)d_in[26];
    const float* lnf_g = (const float*)d_in[27];
    const float* lnf_b = (const float*)d_in[28];
    float* out = (float*)d_out;

    size_t off = 0;
    auto alloc = [&](size_t bytes) {
        void* p = (char*)d_ws + off;
        off += (bytes + 255) & ~(size_t)255;
        return p;
    };
    int* pre = (int*)alloc((size_t)NT * 4);
    unsigned short* s_bf   = (unsigned short*)alloc((size_t)NT * D_MODEL * 2);
    float* h               = (float*)alloc((size_t)NT * D_MODEL * 4);
    unsigned short* a_bf   = (unsigned short*)alloc((size_t)NT * D_MODEL * 2);
    unsigned short* qkv_bf = (unsigned short*)alloc((size_t)NT * 3 * D_MODEL * 2);
    unsigned short* u_bf   = (unsigned short*)alloc((size_t)NT * 4 * D_MODEL * 2);
    unsigned short* h8_bf  = (unsigned short*)alloc((size_t)NT * D_MODEL * 2);
    float* z  = (float*)alloc((size_t)NT * D_MODEL * 4);
    float* dv = (float*)alloc((size_t)NT * D_MODEL * 4);
    float* hn = (float*)alloc((size_t)BATCH * D_MODEL * 4);
    unsigned short* attn_wt  = (unsigned short*)alloc((size_t)2304 * 768 * 2);
    unsigned short* proj_wt  = (unsigned short*)alloc((size_t)768 * 768 * 2);
    unsigned short* fc_wt    = (unsigned short*)alloc((size_t)3072 * 768 * 2);
    unsigned short* mproj_wt = (unsigned short*)alloc((size_t)768 * 3072 * 2);
    unsigned short* wh_t = (unsigned short*)alloc((size_t)768 * 768 * 2);
    unsigned short* ws_t = (unsigned short*)alloc((size_t)768 * 768 * 2);
    unsigned short* wd_t = (unsigned short*)alloc((size_t)768 * 768 * 2);

    dim3 tblk(32, 8);
    scan_kernel<<<1, 64, 0, stream>>>(input_ids, mul, pre);
    embed_kernel<<<NT, 256, 0, stream>>>(input_ids, pre, tok_emb, state_emb,
                                         sp_w, sp_b, wpe, s_bf, h);
    // inject weights (once)
    wconv_t<<<dim3(24, 24), tblk, 0, stream>>>(wh_w, wh_t, 768, 768);
    wconv_t<<<dim3(24, 24), tblk, 0, stream>>>(ws_w, ws_t, 768, 768);
    wconv_t<<<dim3(24, 24), tblk, 0, stream>>>(wd_w, wd_t, 768, 768);

    for (int l = 0; l < L_LAYERS; l++) {
        // convert this layer's weights (stream-ordered; prior GEMMs done first)
        wconv_t<<<dim3(24, 72), tblk, 0, stream>>>(attn_w + (size_t)l * 768 * 2304,
                                                   attn_wt, 768, 2304);
        wconv_t<<<dim3(24, 24), tblk, 0, stream>>>(proj_w + (size_t)l * 768 * 768,
                                                   proj_wt, 768, 768);
        wconv_t<<<dim3(24, 96), tblk, 0, stream>>>(fc_w + (size_t)l * 768 * 3072,
                                                   fc_wt, 768, 3072);
        wconv_t<<<dim3(96, 24), tblk, 0, stream>>>(mproj_w + (size_t)l * 3072 * 768,
                                                   mproj_wt, 3072, 768);

        ln_bf16_kernel<<<NT, 256, 0, stream>>>(h, ln1_g + l * D_MODEL,
                                               ln1_b + l * D_MODEL, a_bf);
        mfma_gemm<<<dim3(NT / 128, 2304 / 128), 256, 0, stream>>>(
            a_bf, attn_wt, attn_b + (size_t)l * 2304, nullptr,
            nullptr, qkv_bf, nullptr, NT, 768, 2304, FLAG_OUTBF16);
        attn_mfma<<<dim3(SEQ / 64, H_HEADS, BATCH), 256, 0, stream>>>(qkv_bf, a_bf);
        mfma_gemm<<<dim3(NT / 128, 768 / 128), 256, 0, stream>>>(
            a_bf, proj_wt, proj_b + (size_t)l * 768, h,
            h, nullptr, nullptr, NT, 768, 768, FLAG_RESID);
        ln_bf16_kernel<<<NT, 256, 0, stream>>>(h, ln2_g + l * D_MODEL,
                                               ln2_b + l * D_MODEL, a_bf);
        mfma_gemm<<<dim3(NT / 128, 3072 / 128), 256, 0, stream>>>(
            a_bf, fc_wt, fc_b + (size_t)l * 3072, nullptr,
            nullptr, u_bf, nullptr, NT, 768, 3072, FLAG_OUTBF16 | FLAG_GELU);
        int mpflags = FLAG_RESID | (l == INJECT_L ? FLAG_MIRROR : 0);
        mfma_gemm<<<dim3(NT / 128, 768 / 128), 256, 0, stream>>>(
            u_bf, mproj_wt, mproj_b + (size_t)l * 768, h,
            h, nullptr, h8_bf, NT, 3072, 768, mpflags);

        if (l == INJECT_L) {
            mfma_gemm<<<dim3(NT / 128, 768 / 128), 256, 0, stream>>>(
                h8_bf, wh_t, wh_b, nullptr, z, nullptr, nullptr, NT, 768, 768, 0);
            mfma_gemm<<<dim3(NT / 128, 768 / 128), 256, 0, stream>>>(
                s_bf, ws_t, ws_b, z, z, nullptr, nullptr, NT, 768, 768, FLAG_RESID);
            mfma_gemm<<<dim3(NT / 128, 768 / 128), 256, 0, stream>>>(
                s_bf, wd_t, wd_b, nullptr, dv, nullptr, nullptr, NT, 768, 768, 0);
            gate_kernel<<<dim3(2048), 256, 0, stream>>>(h, z, dv, (size_t)NT * D_MODEL);
        }
    }

    ln_f32_kernel<<<BATCH, 256, 0, stream>>>(h + (size_t)(SEQ - 1) * D_MODEL,
                                             lnf_g, lnf_b, hn,
                                             (long)SEQ * D_MODEL, D_MODEL);
    head_kernel<<<BATCH, 64, 0, stream>>>(hn, head_w, head_b, out);
}

// Round 3
// 5294.512 us; speedup vs baseline: 9.3941x; 1.0033x over previous
//
#include <hip/hip_runtime.h>
#include <hip/hip_bf16.h>
#include <math.h>

#define L_LAYERS 12
#define D_MODEL 768
#define H_HEADS 12
#define HD 64
#define NTOK 60
#define DST 128
#define BATCH 8
#define SEQ 1024
#define NT (BATCH * SEQ)
#define INJECT_L 8

typedef short bf16x8 __attribute__((ext_vector_type(8)));
typedef float f32x4 __attribute__((ext_vector_type(4)));
typedef unsigned short u16x4 __attribute__((ext_vector_type(4)));

__device__ __forceinline__ unsigned short f2bf(float f) {
    unsigned int u = __float_as_uint(f);
    u = (u + 0x7FFF + ((u >> 16) & 1)) >> 16;   // RNE
    return (unsigned short)u;
}

// gelu_tanh(x) = 0.5x(1+tanh(c)) = x * sigmoid(2c),  c = 0.79788456*(x+0.044715x^3)
__device__ __forceinline__ float gelu_fast(float x) {
    float two_c = 1.5957691216057308f * (x + 0.044715f * x * x * x);
    return x / (1.0f + __expf(-two_c));
}

__device__ __forceinline__ void async_copy16(void* lds, const void* gmem) {
    __builtin_amdgcn_global_load_lds(
        (const __attribute__((address_space(1))) unsigned int*)gmem,
        (__attribute__((address_space(3))) unsigned int*)lds,
        16, 0, 0);
}

// ---------------------------------------------------------------------------
// Parallel chunked scan. One block per batch. Chunk = 16 steps.
// ---------------------------------------------------------------------------
__global__ __launch_bounds__(1024) void scan_kernel(const int* __restrict__ ids,
                                                    const int* __restrict__ mul,
                                                    int* __restrict__ pre) {
    __shared__ int smul[NTOK * NTOK];
    __shared__ int sids[SEQ];
    __shared__ int Mc[64 * NTOK];
    __shared__ int entry[64];
    int b = blockIdx.x;
    int tid = threadIdx.x;
    for (int i = tid; i < NTOK * NTOK; i += 1024) smul[i] = mul[i];
    for (int i = tid; i < SEQ; i += 1024) sids[i] = ids[b * SEQ + i];
    __syncthreads();
    // phase 1: per-chunk composed maps (64 chunks x 60 states)
    for (int task = tid; task < 64 * NTOK; task += 1024) {
        int c = task / NTOK, s = task - c * NTOK;
        int st = s;
        #pragma unroll
        for (int j = 0; j < 16; j++) st = smul[sids[c * 16 + j] * NTOK + st];
        Mc[c * NTOK + s] = st;
    }
    __syncthreads();
    // phase 2: serial compose over 64 chunks
    if (tid == 0) {
        int st = 0;
        for (int c = 0; c < 64; c++) { entry[c] = st; st = Mc[c * NTOK + st]; }
    }
    __syncthreads();
    // phase 3: rewalk chunks, emit pre-states
    if (tid < 64) {
        int c = tid;
        int st = entry[c];
        int* pr = pre + b * SEQ + c * 16;
        #pragma unroll
        for (int j = 0; j < 16; j++) {
            pr[j] = st;
            st = smul[sids[c * 16 + j] * NTOK + st];
        }
    }
}

// ---------------------------------------------------------------------------
// State projection table: stable[st] = state_emb[st] @ sp_w + sp_b  (60 x 768)
// ---------------------------------------------------------------------------
__global__ __launch_bounds__(256) void state_table_kernel(const float* __restrict__ state_emb,
                                                          const float* __restrict__ sp_w,
                                                          const float* __restrict__ sp_b,
                                                          float* __restrict__ stable) {
    int st = blockIdx.x;
    __shared__ float se[DST];
    if (threadIdx.x < DST) se[threadIdx.x] = state_emb[st * DST + threadIdx.x];
    __syncthreads();
    for (int d = threadIdx.x; d < D_MODEL; d += 256) {
        float acc = sp_b[d];
        #pragma unroll 8
        for (int k = 0; k < DST; k++) acc += se[k] * sp_w[k * D_MODEL + d];
        stable[st * D_MODEL + d] = acc;
    }
}

// ---------------------------------------------------------------------------
// Embed gather: h = tok_emb[id] + stable[pre] + wpe[t]; s_bf = bf16(stable[pre])
// one wave per row, float4
// ---------------------------------------------------------------------------
__global__ __launch_bounds__(64) void embed_gather(const int* __restrict__ ids,
                                                   const int* __restrict__ pre,
                                                   const float* __restrict__ tok_emb,
                                                   const float* __restrict__ stable,
                                                   const float* __restrict__ wpe,
                                                   unsigned short* __restrict__ s_bf,
                                                   float* __restrict__ h) {
    int n = blockIdx.x;
    int t = n & (SEQ - 1);
    int lane = threadIdx.x;
    const float4* te = (const float4*)(tok_emb + (size_t)ids[n] * D_MODEL);
    const float4* sv = (const float4*)(stable + (size_t)pre[n] * D_MODEL);
    const float4* wp = (const float4*)(wpe + (size_t)t * D_MODEL);
    float4* hr = (float4*)(h + (size_t)n * D_MODEL);
    unsigned short* sr = s_bf + (size_t)n * D_MODEL;
    #pragma unroll
    for (int j = 0; j < 3; j++) {
        int idx = j * 64 + lane;
        float4 a = te[idx], b = sv[idx], c = wp[idx];
        float4 o;
        o.x = a.x + b.x + c.x; o.y = a.y + b.y + c.y;
        o.z = a.z + b.z + c.z; o.w = a.w + b.w + c.w;
        hr[idx] = o;
        u16x4 pk = { f2bf(b.x), f2bf(b.y), f2bf(b.z), f2bf(b.w) };
        *(u16x4*)&sr[idx * 4] = pk;
    }
}

// ---------------------------------------------------------------------------
// LayerNorm, one wave per row, float4. fp32->bf16.
// ---------------------------------------------------------------------------
__global__ __launch_bounds__(256) void ln_bf16_kernel(const float* __restrict__ x,
                                                      const float* __restrict__ g,
                                                      const float* __restrict__ bta,
                                                      unsigned short* __restrict__ out) {
    int row = blockIdx.x * 4 + (threadIdx.x >> 6);
    int lane = threadIdx.x & 63;
    const float4* xr = (const float4*)(x + (size_t)row * D_MODEL);
    float4 v[3];
    float sum = 0.f, sq = 0.f;
    #pragma unroll
    for (int j = 0; j < 3; j++) {
        v[j] = xr[j * 64 + lane];
        sum += v[j].x + v[j].y + v[j].z + v[j].w;
        sq += v[j].x * v[j].x + v[j].y * v[j].y + v[j].z * v[j].z + v[j].w * v[j].w;
    }
    for (int off = 32; off; off >>= 1) {
        sum += __shfl_xor(sum, off);
        sq += __shfl_xor(sq, off);
    }
    float mean = sum * (1.0f / D_MODEL);
    float var = sq * (1.0f / D_MODEL) - mean * mean;
    float r = rsqrtf(var + 1e-5f);
    const float4* g4 = (const float4*)g;
    const float4* b4 = (const float4*)bta;
    unsigned short* orow = out + (size_t)row * D_MODEL;
    #pragma unroll
    for (int j = 0; j < 3; j++) {
        int idx = j * 64 + lane;
        float4 gg = g4[idx], bb = b4[idx];
        u16x4 pk = { f2bf((v[j].x - mean) * r * gg.x + bb.x),
                     f2bf((v[j].y - mean) * r * gg.y + bb.y),
                     f2bf((v[j].z - mean) * r * gg.z + bb.z),
                     f2bf((v[j].w - mean) * r * gg.w + bb.w) };
        *(u16x4*)&orow[idx * 4] = pk;
    }
}

// fp32->fp32 LN for lnf (8 rows), block 256, strided input
__global__ __launch_bounds__(256) void ln_f32_kernel(const float* __restrict__ x,
                                                     const float* __restrict__ g,
                                                     const float* __restrict__ bta,
                                                     float* __restrict__ out,
                                                     long in_stride, long out_stride) {
    long row = blockIdx.x;
    const float* xr = x + row * in_stride;
    int tid = threadIdx.x;
    float v0 = xr[tid], v1 = xr[tid + 256], v2 = xr[tid + 512];
    float sum = v0 + v1 + v2;
    float sq = v0 * v0 + v1 * v1 + v2 * v2;
    for (int off = 32; off; off >>= 1) {
        sum += __shfl_xor(sum, off);
        sq += __shfl_xor(sq, off);
    }
    __shared__ float red[8];
    int wid = tid >> 6;
    if ((tid & 63) == 0) { red[wid] = sum; red[4 + wid] = sq; }
    __syncthreads();
    sum = red[0] + red[1] + red[2] + red[3];
    sq = red[4] + red[5] + red[6] + red[7];
    float mean = sum * (1.0f / D_MODEL);
    float var = sq * (1.0f / D_MODEL) - mean * mean;
    float r = rsqrtf(var + 1e-5f);
    float* orow = out + row * out_stride;
    orow[tid] = (v0 - mean) * r * g[tid] + bta[tid];
    orow[tid + 256] = (v1 - mean) * r * g[tid + 256] + bta[tid + 256];
    orow[tid + 512] = (v2 - mean) * r * g[tid + 512] + bta[tid + 512];
}

// ---------------------------------------------------------------------------
// Fused per-layer weight conversion: 4 matrices, flat 32x32 tile grid.
// tiles: attn 24x72=1728 | proj 24x24=576 | fc 24x96=2304 | mproj 96x24=2304
// total 6912
// ---------------------------------------------------------------------------
__device__ __forceinline__ void conv_tile(const float* __restrict__ src,
                                          unsigned short* __restrict__ dst,
                                          int R, int C, int rt, int ct,
                                          int tc, int tr) {
    __shared__ float tile[32][33];
    int r0 = rt * 32, c0 = ct * 32;
    #pragma unroll
    for (int i = 0; i < 32; i += 8)
        tile[tr + i][tc] = src[(size_t)(r0 + tr + i) * C + c0 + tc];
    __syncthreads();
    #pragma unroll
    for (int i = 0; i < 32; i += 8)
        dst[(size_t)(c0 + tr + i) * R + r0 + tc] = f2bf(tile[tc][tr + i]);
}

__global__ __launch_bounds__(256) void wconv_layer(const float* __restrict__ attn_w,
                                                   const float* __restrict__ proj_w,
                                                   const float* __restrict__ fc_w,
                                                   const float* __restrict__ mproj_w,
                                                   unsigned short* __restrict__ attn_wt,
                                                   unsigned short* __restrict__ proj_wt,
                                                   unsigned short* __restrict__ fc_wt,
                                                   unsigned short* __restrict__ mproj_wt) {
    int bid = blockIdx.x;
    const float* src; unsigned short* dst; int R, C, CT, tloc;
    if (bid < 1728)      { src = attn_w;  dst = attn_wt;  R = 768;  C = 2304; CT = 72; tloc = bid; }
    else if (bid < 2304) { src = proj_w;  dst = proj_wt;  R = 768;  C = 768;  CT = 24; tloc = bid - 1728; }
    else if (bid < 4608) { src = fc_w;    dst = fc_wt;    R = 768;  C = 3072; CT = 96; tloc = bid - 2304; }
    else                 { src = mproj_w; dst = mproj_wt; R = 3072; C = 768;  CT = 24; tloc = bid - 4608; }
    int rt = tloc / CT, ct = tloc - rt * CT;
    conv_tile(src, dst, R, C, rt, ct, threadIdx.x, threadIdx.y);
}

__global__ __launch_bounds__(256) void wconv_inject(const float* __restrict__ wh_w,
                                                    const float* __restrict__ ws_w,
                                                    const float* __restrict__ wd_w,
                                                    unsigned short* __restrict__ wh_t,
                                                    unsigned short* __restrict__ ws_t,
                                                    unsigned short* __restrict__ wd_t) {
    int bid = blockIdx.x;
    int sel = bid / 576, tloc = bid - sel * 576;
    const float* src = sel == 0 ? wh_w : (sel == 1 ? ws_w : wd_w);
    unsigned short* dst = sel == 0 ? wh_t : (sel == 1 ? ws_t : wd_t);
    int rt = tloc / 24, ct = tloc - rt * 24;
    conv_tile(src, dst, 768, 768, rt, ct, threadIdx.x, threadIdx.y);
}

// ---------------------------------------------------------------------------
// bf16 MFMA GEMM, 128x128 tile, BK=32, XOR-swizzled LDS (conflict-free reads)
// ---------------------------------------------------------------------------
#define FLAG_OUTBF16 1
#define FLAG_GELU 2
#define FLAG_RESID 4
#define FLAG_MIRROR 8

__global__ __launch_bounds__(256) void mfma_gemm(const unsigned short* __restrict__ A,
                                                 const unsigned short* __restrict__ Wt,
                                                 const float* __restrict__ bias,
                                                 const float* __restrict__ residual,
                                                 float* __restrict__ Cf,
                                                 unsigned short* __restrict__ Cb,
                                                 unsigned short* __restrict__ Cmir,
                                                 int M, int K, int N, int flags) {
    __shared__ unsigned short As[128 * 32];
    __shared__ unsigned short Bs[128 * 32];
    int tid = threadIdx.x;
    int wave = tid >> 6, lane = tid & 63;
    int quad = lane >> 4, l16 = lane & 15;
    int m0 = blockIdx.x * 128, n0 = blockIdx.y * 128;
    int wm = (wave & 1) * 64, wn = (wave >> 1) * 64;
    f32x4 acc[4][4] = {};

    // staging: lane p loads swizzled chunk so that fragment reads are 2-way
    int cl = (lane & ~3) | ((lane & 3) ^ ((lane >> 3) & 3));
    int quadS = quad ^ ((l16 >> 1) & 3);    // read-side swizzled quad

    for (int k0 = 0; k0 < K; k0 += 32) {
        #pragma unroll
        for (int i = 0; i < 2; i++) {
            int chunk = i * 256 + wave * 64 + cl;
            int r = chunk >> 2, cc = chunk & 3;
            async_copy16(&As[(i * 256 + wave * 64) * 8],
                         A + (size_t)(m0 + r) * K + k0 + cc * 8);
            async_copy16(&Bs[(i * 256 + wave * 64) * 8],
                         Wt + (size_t)(n0 + r) * K + k0 + cc * 8);
        }
        __syncthreads();
        bf16x8 af[4], bfr[4];
        #pragma unroll
        for (int mi = 0; mi < 4; mi++)
            af[mi] = *(const bf16x8*)&As[(wm + mi * 16 + l16) * 32 + quadS * 8];
        #pragma unroll
        for (int ni = 0; ni < 4; ni++)
            bfr[ni] = *(const bf16x8*)&Bs[(wn + ni * 16 + l16) * 32 + quadS * 8];
        #pragma unroll
        for (int mi = 0; mi < 4; mi++)
            #pragma unroll
            for (int ni = 0; ni < 4; ni++)
                acc[mi][ni] = __builtin_amdgcn_mfma_f32_16x16x32_bf16(
                    af[mi], bfr[ni], acc[mi][ni], 0, 0, 0);
        __syncthreads();
    }
    #pragma unroll
    for (int mi = 0; mi < 4; mi++) {
        #pragma unroll
        for (int ni = 0; ni < 4; ni++) {
            int col = n0 + wn + ni * 16 + l16;
            float bv = bias[col];
            #pragma unroll
            for (int r = 0; r < 4; r++) {
                int row = m0 + wm + mi * 16 + quad * 4 + r;
                size_t idx = (size_t)row * N + col;
                float v = acc[mi][ni][r] + bv;
                if (flags & FLAG_RESID) v += residual[idx];
                if (flags & FLAG_GELU) v = gelu_fast(v);
                if (flags & FLAG_OUTBF16) Cb[idx] = f2bf(v);
                else Cf[idx] = v;
                if (flags & FLAG_MIRROR) Cmir[idx] = f2bf(v);
            }
        }
    }
}

// ---------------------------------------------------------------------------
// Flash attention, bf16 MFMA, 64-query tile per block, 64-key steps.
// ---------------------------------------------------------------------------
__global__ __launch_bounds__(256) void attn_mfma(const unsigned short* __restrict__ qkv,
                                                 unsigned short* __restrict__ o) {
    int qt = blockIdx.x, hh = blockIdx.y, b = blockIdx.z;
    int tid = threadIdx.x, wave = tid >> 6, lane = tid & 63;
    int quad = lane >> 4, l16 = lane & 15;
    __shared__ unsigned short Qs[64][72];
    __shared__ unsigned short Ks[64][72];
    __shared__ unsigned short Vt[64][72];
    __shared__ unsigned short Ps[4][16][72];
    const size_t rstride = 3 * D_MODEL;
    int q0 = qt * 64;

    {
        size_t qbase = ((size_t)(b * SEQ + q0)) * rstride + hh * HD;
        #pragma unroll
        for (int i = 0; i < 2; i++) {
            int chunk = i * 256 + tid;
            int r = chunk >> 3, cc = chunk & 7;
            *(uint4*)&Qs[r][cc * 8] =
                *(const uint4*)(qkv + qbase + (size_t)r * rstride + cc * 8);
        }
    }

    float m_r[4] = {-1e30f, -1e30f, -1e30f, -1e30f};
    float l_r[4] = {0.f, 0.f, 0.f, 0.f};
    f32x4 oacc[4] = {};

    for (int kt = 0; kt <= qt; kt++) {
        int kb = kt * 64;
        __syncthreads();
        size_t kbase = ((size_t)(b * SEQ + kb)) * rstride + D_MODEL + hh * HD;
        size_t vbase = ((size_t)(b * SEQ + kb)) * rstride + 2 * D_MODEL + hh * HD;
        #pragma unroll
        for (int i = 0; i < 2; i++) {
            int chunk = i * 256 + tid;
            int r = chunk >> 3, cc = chunk & 7;
            *(uint4*)&Ks[r][cc * 8] =
                *(const uint4*)(qkv + kbase + (size_t)r * rstride + cc * 8);
        }
        #pragma unroll
        for (int i = 0; i < 2; i++) {
            int chunk = i * 256 + tid;
            int key = chunk >> 3, dg = chunk & 7;
            uint4 vv = *(const uint4*)(qkv + vbase + (size_t)key * rstride + dg * 8);
            const unsigned short* vs = (const unsigned short*)&vv;
            #pragma unroll
            for (int j = 0; j < 8; j++) Vt[dg * 8 + j][key] = vs[j];
        }
        __syncthreads();

        f32x4 sacc[4] = {};
        bf16x8 qf0 = *(const bf16x8*)&Qs[wave * 16 + l16][quad * 8];
        bf16x8 qf1 = *(const bf16x8*)&Qs[wave * 16 + l16][32 + quad * 8];
        #pragma unroll
        for (int ni = 0; ni < 4; ni++) {
            bf16x8 kf0 = *(const bf16x8*)&Ks[ni * 16 + l16][quad * 8];
            bf16x8 kf1 = *(const bf16x8*)&Ks[ni * 16 + l16][32 + quad * 8];
            sacc[ni] = __builtin_amdgcn_mfma_f32_16x16x32_bf16(qf0, kf0, sacc[ni], 0, 0, 0);
            sacc[ni] = __builtin_amdgcn_mfma_f32_16x16x32_bf16(qf1, kf1, sacc[ni], 0, 0, 0);
        }

        bool diag = (kt == qt);
        const float scale = 0.125f;
        #pragma unroll
        for (int r = 0; r < 4; r++) {
            int qrow_loc = wave * 16 + quad * 4 + r;
            float mx = m_r[r];
            #pragma unroll
            for (int ni = 0; ni < 4; ni++) {
                float sv = sacc[ni][r] * scale;
                if (diag && (ni * 16 + l16 > qrow_loc)) sv = -1e30f;
                sacc[ni][r] = sv;
                mx = fmaxf(mx, sv);
            }
            for (int off = 8; off; off >>= 1) mx = fmaxf(mx, __shfl_xor(mx, off));
            float alpha = __expf(m_r[r] - mx);
            m_r[r] = mx;
            float ls = 0.f;
            #pragma unroll
            for (int ni = 0; ni < 4; ni++) {
                float p = __expf(sacc[ni][r] - mx);
                sacc[ni][r] = p;
                ls += p;
            }
            for (int off = 8; off; off >>= 1) ls += __shfl_xor(ls, off);
            l_r[r] = l_r[r] * alpha + ls;
            #pragma unroll
            for (int ni = 0; ni < 4; ni++) oacc[ni][r] *= alpha;
        }

        #pragma unroll
        for (int ni = 0; ni < 4; ni++)
            #pragma unroll
            for (int r = 0; r < 4; r++)
                Ps[wave][quad * 4 + r][ni * 16 + l16] = f2bf(sacc[ni][r]);
        asm volatile("s_waitcnt lgkmcnt(0)" ::: "memory");

        bf16x8 pf0 = *(const bf16x8*)&Ps[wave][l16][quad * 8];
        bf16x8 pf1 = *(const bf16x8*)&Ps[wave][l16][32 + quad * 8];
        #pragma unroll
        for (int ni = 0; ni < 4; ni++) {
            bf16x8 vf0 = *(const bf16x8*)&Vt[ni * 16 + l16][quad * 8];
            bf16x8 vf1 = *(const bf16x8*)&Vt[ni * 16 + l16][32 + quad * 8];
            oacc[ni] = __builtin_amdgcn_mfma_f32_16x16x32_bf16(pf0, vf0, oacc[ni], 0, 0, 0);
            oacc[ni] = __builtin_amdgcn_mfma_f32_16x16x32_bf16(pf1, vf1, oacc[ni], 0, 0, 0);
        }
    }

    #pragma unroll
    for (int ni = 0; ni < 4; ni++) {
        #pragma unroll
        for (int r = 0; r < 4; r++) {
            float inv = 1.0f / l_r[r];
            int row = q0 + wave * 16 + quad * 4 + r;
            o[((size_t)(b * SEQ + row)) * D_MODEL + hh * HD + ni * 16 + l16] =
                f2bf(oacc[ni][r] * inv);
        }
    }
}

// ---------------------------------------------------------------------------
__global__ __launch_bounds__(256) void gate_kernel(float* __restrict__ h,
                                                   const float* __restrict__ z,
                                                   const float* __restrict__ dv,
                                                   size_t total) {
    size_t i = (size_t)blockIdx.x * blockDim.x + threadIdx.x;
    size_t stride = (size_t)gridDim.x * blockDim.x;
    for (; i < total; i += stride) {
        float g = 1.0f / (1.0f + __expf(-z[i]));
        h[i] += g * dv[i];
    }
}

__global__ __launch_bounds__(64) void head_kernel(const float* __restrict__ hn,
                                                  const float* __restrict__ head_w,
                                                  const float* __restrict__ head_b,
                                                  float* __restrict__ out) {
    int b = blockIdx.x;
    int n = threadIdx.x;
    if (n < NTOK) {
        float acc = head_b[n];
        const float* hr = hn + b * D_MODEL;
        for (int k = 0; k < D_MODEL; k++) acc += hr[k] * head_w[k * NTOK + n];
        out[b * NTOK + n] = acc;
    }
}

// ---------------------------------------------------------------------------
extern "C" void kernel_launch(void* const* d_in, const int* in_sizes, int n_in,
                              void* d_out, int out_size, void* d_ws, size_t ws_size,
                              hipStream_t stream) {
    (void)in_sizes; (void)n_in; (void)out_size; (void)ws_size;
    const int* input_ids = (const int*)d_in[0];
    const int* mul       = (const int*)d_in[1];
    const float* tok_emb = (const float*)d_in[2];
    const float* state_emb = (const float*)d_in[3];
    const float* sp_w = (const float*)d_in[4];
    const float* sp_b = (const float*)d_in[5];
    const float* wh_w = (const float*)d_in[6];
    const float* wh_b = (const float*)d_in[7];
    const float* ws_w = (const float*)d_in[8];
    const float* ws_b = (const float*)d_in[9];
    const float* wd_w = (const float*)d_in[10];
    const float* wd_b = (const float*)d_in[11];
    const float* head_w = (const float*)d_in[12];
    const float* head_b = (const float*)d_in[13];
    const float* wpe  = (const float*)d_in[14];
    const float* ln1_g = (const float*)d_in[15];
    const float* ln1_b = (const float*)d_in[16];
    const float* attn_w = (const float*)d_in[17];
    const float* attn_b = (const float*)d_in[18];
    const float* proj_w = (const float*)d_in[19];
    const float* proj_b = (const float*)d_in[20];
    const float* ln2_g = (const float*)d_in[21];
    const float* ln2_b = (const float*)d_in[22];
    const float* fc_w = (const float*)d_in[23];
    const float* fc_b = (const float*)d_in[24];
    const float* mproj_w = (const float*)d_in[25];
    const float* mproj_b = (const float*)d_in[26];
    const float* lnf_g = (const float*)d_in[27];
    const float* lnf_b = (const float*)d_in[28];
    float* out = (float*)d_out;

    size_t off = 0;
    auto alloc = [&](size_t bytes) {
        void* p = (char*)d_ws + off;
        off += (bytes + 255) & ~(size_t)255;
        return p;
    };
    int* pre = (int*)alloc((size_t)NT * 4);
    float* stable = (float*)alloc((size_t)NTOK * D_MODEL * 4);
    unsigned short* s_bf   = (unsigned short*)alloc((size_t)NT * D_MODEL * 2);
    float* h               = (float*)alloc((size_t)NT * D_MODEL * 4);
    unsigned short* a_bf   = (unsigned short*)alloc((size_t)NT * D_MODEL * 2);
    unsigned short* qkv_bf = (unsigned short*)alloc((size_t)NT * 3 * D_MODEL * 2);
    unsigned short* u_bf   = (unsigned short*)alloc((size_t)NT * 4 * D_MODEL * 2);
    unsigned short* h8_bf  = (unsigned short*)alloc((size_t)NT * D_MODEL * 2);
    float* z  = (float*)alloc((size_t)NT * D_MODEL * 4);
    float* dv = (float*)alloc((size_t)NT * D_MODEL * 4);
    float* hn = (float*)alloc((size_t)BATCH * D_MODEL * 4);
    unsigned short* attn_wt  = (unsigned short*)alloc((size_t)2304 * 768 * 2);
    unsigned short* proj_wt  = (unsigned short*)alloc((size_t)768 * 768 * 2);
    unsigned short* fc_wt    = (unsigned short*)alloc((size_t)3072 * 768 * 2);
    unsigned short* mproj_wt = (unsigned short*)alloc((size_t)768 * 3072 * 2);
    unsigned short* wh_t = (unsigned short*)alloc((size_t)768 * 768 * 2);
    unsigned short* ws_t = (unsigned short*)alloc((size_t)768 * 768 * 2);
    unsigned short* wd_t = (unsigned short*)alloc((size_t)768 * 768 * 2);

    scan_kernel<<<BATCH, 1024, 0, stream>>>(input_ids, mul, pre);
    state_table_kernel<<<NTOK, 256, 0, stream>>>(state_emb, sp_w, sp_b, stable);
    embed_gather<<<NT, 64, 0, stream>>>(input_ids, pre, tok_emb, stable, wpe, s_bf, h);
    wconv_inject<<<1728, dim3(32, 8), 0, stream>>>(wh_w, ws_w, wd_w, wh_t, ws_t, wd_t);

    for (int l = 0; l < L_LAYERS; l++) {
        wconv_layer<<<6912, dim3(32, 8), 0, stream>>>(
            attn_w + (size_t)l * 768 * 2304, proj_w + (size_t)l * 768 * 768,
            fc_w + (size_t)l * 768 * 3072, mproj_w + (size_t)l * 3072 * 768,
            attn_wt, proj_wt, fc_wt, mproj_wt);

        ln_bf16_kernel<<<NT / 4, 256, 0, stream>>>(h, ln1_g + l * D_MODEL,
                                                   ln1_b + l * D_MODEL, a_bf);
        mfma_gemm<<<dim3(NT / 128, 2304 / 128), 256, 0, stream>>>(
            a_bf, attn_wt, attn_b + (size_t)l * 2304, nullptr,
            nullptr, qkv_bf, nullptr, NT, 768, 2304, FLAG_OUTBF16);
        attn_mfma<<<dim3(SEQ / 64, H_HEADS, BATCH), 256, 0, stream>>>(qkv_bf, a_bf);
        mfma_gemm<<<dim3(NT / 128, 768 / 128), 256, 0, stream>>>(
            a_bf, proj_wt, proj_b + (size_t)l * 768, h,
            h, nullptr, nullptr, NT, 768, 768, FLAG_RESID);
        ln_bf16_kernel<<<NT / 4, 256, 0, stream>>>(h, ln2_g + l * D_MODEL,
                                                   ln2_b + l * D_MODEL, a_bf);
        mfma_gemm<<<dim3(NT / 128, 3072 / 128), 256, 0, stream>>>(
            a_bf, fc_wt, fc_b + (size_t)l * 3072, nullptr,
            nullptr, u_bf, nullptr, NT, 768, 3072, FLAG_OUTBF16 | FLAG_GELU);
        int mpflags = FLAG_RESID | (l == INJECT_L ? FLAG_MIRROR : 0);
        mfma_gemm<<<dim3(NT / 128, 768 / 128), 256, 0, stream>>>(
            u_bf, mproj_wt, mproj_b + (size_t)l * 768, h,
            h, nullptr, h8_bf, NT, 3072, 768, mpflags);

        if (l == INJECT_L) {
            mfma_gemm<<<dim3(NT / 128, 768 / 128), 256, 0, stream>>>(
                h8_bf, wh_t, wh_b, nullptr, z, nullptr, nullptr, NT, 768, 768, 0);
            mfma_gemm<<<dim3(NT / 128, 768 / 128), 256, 0, stream>>>(
                s_bf, ws_t, ws_b, z, z, nullptr, nullptr, NT, 768, 768, FLAG_RESID);
            mfma_gemm<<<dim3(NT / 128, 768 / 128), 256, 0, stream>>>(
                s_bf, wd_t, wd_b, nullptr, dv, nullptr, nullptr, NT, 768, 768, 0);
            gate_kernel<<<dim3(2048), 256, 0, stream>>>(h, z, dv, (size_t)NT * D_MODEL);
        }
    }

    ln_f32_kernel<<<BATCH, 256, 0, stream>>>(h + (size_t)(SEQ - 1) * D_MODEL,
                                             lnf_g, lnf_b, hn,
                                             (long)SEQ * D_MODEL, D_MODEL);
    head_kernel<<<BATCH, 64, 0, stream>>>(hn, head_w, head_b, out);
}

// Round 4
// 4600.258 us; speedup vs baseline: 10.8118x; 1.1509x over previous
//
#include <hip/hip_runtime.h>
#include <hip/hip_bf16.h>
#include <math.h>

#define L_LAYERS 12
#define D_MODEL 768
#define H_HEADS 12
#define HD 64
#define NTOK 60
#define DST 128
#define BATCH 8
#define SEQ 1024
#define NT (BATCH * SEQ)
#define INJECT_L 8

typedef short bf16x8 __attribute__((ext_vector_type(8)));
typedef float f32x4 __attribute__((ext_vector_type(4)));
typedef unsigned short u16x4 __attribute__((ext_vector_type(4)));

__device__ __forceinline__ unsigned short f2bf(float f) {
    unsigned int u = __float_as_uint(f);
    u = (u + 0x7FFF + ((u >> 16) & 1)) >> 16;   // RNE
    return (unsigned short)u;
}

// gelu_tanh(x) = 0.5x(1+tanh(c)) = x * sigmoid(2c)
__device__ __forceinline__ float gelu_fast(float x) {
    float two_c = 1.5957691216057308f * (x + 0.044715f * x * x * x);
    return x / (1.0f + __expf(-two_c));
}

__device__ __forceinline__ void async_copy16(void* lds, const void* gmem) {
    __builtin_amdgcn_global_load_lds(
        (const __attribute__((address_space(1))) unsigned int*)gmem,
        (__attribute__((address_space(3))) unsigned int*)lds,
        16, 0, 0);
}

// ---------------------------------------------------------------------------
// Parallel chunked scan. One block per batch. Chunk = 16 steps.
// ---------------------------------------------------------------------------
__global__ __launch_bounds__(1024) void scan_kernel(const int* __restrict__ ids,
                                                    const int* __restrict__ mul,
                                                    int* __restrict__ pre) {
    __shared__ int smul[NTOK * NTOK];
    __shared__ int sids[SEQ];
    __shared__ int Mc[64 * NTOK];
    __shared__ int entry[64];
    int b = blockIdx.x;
    int tid = threadIdx.x;
    for (int i = tid; i < NTOK * NTOK; i += 1024) smul[i] = mul[i];
    for (int i = tid; i < SEQ; i += 1024) sids[i] = ids[b * SEQ + i];
    __syncthreads();
    for (int task = tid; task < 64 * NTOK; task += 1024) {
        int c = task / NTOK, s = task - c * NTOK;
        int st = s;
        #pragma unroll
        for (int j = 0; j < 16; j++) st = smul[sids[c * 16 + j] * NTOK + st];
        Mc[c * NTOK + s] = st;
    }
    __syncthreads();
    if (tid == 0) {
        int st = 0;
        for (int c = 0; c < 64; c++) { entry[c] = st; st = Mc[c * NTOK + st]; }
    }
    __syncthreads();
    if (tid < 64) {
        int c = tid;
        int st = entry[c];
        int* pr = pre + b * SEQ + c * 16;
        #pragma unroll
        for (int j = 0; j < 16; j++) {
            pr[j] = st;
            st = smul[sids[c * 16 + j] * NTOK + st];
        }
    }
}

// ---------------------------------------------------------------------------
// State projection table: stable[st] = state_emb[st] @ sp_w + sp_b  (60 x 768)
// ---------------------------------------------------------------------------
__global__ __launch_bounds__(256) void state_table_kernel(const float* __restrict__ state_emb,
                                                          const float* __restrict__ sp_w,
                                                          const float* __restrict__ sp_b,
                                                          float* __restrict__ stable) {
    int st = blockIdx.x;
    __shared__ float se[DST];
    if (threadIdx.x < DST) se[threadIdx.x] = state_emb[st * DST + threadIdx.x];
    __syncthreads();
    for (int d = threadIdx.x; d < D_MODEL; d += 256) {
        float acc = sp_b[d];
        #pragma unroll 8
        for (int k = 0; k < DST; k++) acc += se[k] * sp_w[k * D_MODEL + d];
        stable[st * D_MODEL + d] = acc;
    }
}

// ---------------------------------------------------------------------------
// Embed gather: h = tok_emb[id] + stable[pre] + wpe[t]; s_bf = bf16(stable[pre])
// ---------------------------------------------------------------------------
__global__ __launch_bounds__(64) void embed_gather(const int* __restrict__ ids,
                                                   const int* __restrict__ pre,
                                                   const float* __restrict__ tok_emb,
                                                   const float* __restrict__ stable,
                                                   const float* __restrict__ wpe,
                                                   unsigned short* __restrict__ s_bf,
                                                   float* __restrict__ h) {
    int n = blockIdx.x;
    int t = n & (SEQ - 1);
    int lane = threadIdx.x;
    const float4* te = (const float4*)(tok_emb + (size_t)ids[n] * D_MODEL);
    const float4* sv = (const float4*)(stable + (size_t)pre[n] * D_MODEL);
    const float4* wp = (const float4*)(wpe + (size_t)t * D_MODEL);
    float4* hr = (float4*)(h + (size_t)n * D_MODEL);
    unsigned short* sr = s_bf + (size_t)n * D_MODEL;
    #pragma unroll
    for (int j = 0; j < 3; j++) {
        int idx = j * 64 + lane;
        float4 a = te[idx], b = sv[idx], c = wp[idx];
        float4 o;
        o.x = a.x + b.x + c.x; o.y = a.y + b.y + c.y;
        o.z = a.z + b.z + c.z; o.w = a.w + b.w + c.w;
        hr[idx] = o;
        u16x4 pk = { f2bf(b.x), f2bf(b.y), f2bf(b.z), f2bf(b.w) };
        *(u16x4*)&sr[idx * 4] = pk;
    }
}

// ---------------------------------------------------------------------------
// LayerNorm, one wave per row, float4. fp32->bf16.
// ---------------------------------------------------------------------------
__global__ __launch_bounds__(256) void ln_bf16_kernel(const float* __restrict__ x,
                                                      const float* __restrict__ g,
                                                      const float* __restrict__ bta,
                                                      unsigned short* __restrict__ out) {
    int row = blockIdx.x * 4 + (threadIdx.x >> 6);
    int lane = threadIdx.x & 63;
    const float4* xr = (const float4*)(x + (size_t)row * D_MODEL);
    float4 v[3];
    float sum = 0.f, sq = 0.f;
    #pragma unroll
    for (int j = 0; j < 3; j++) {
        v[j] = xr[j * 64 + lane];
        sum += v[j].x + v[j].y + v[j].z + v[j].w;
        sq += v[j].x * v[j].x + v[j].y * v[j].y + v[j].z * v[j].z + v[j].w * v[j].w;
    }
    for (int off = 32; off; off >>= 1) {
        sum += __shfl_xor(sum, off);
        sq += __shfl_xor(sq, off);
    }
    float mean = sum * (1.0f / D_MODEL);
    float var = sq * (1.0f / D_MODEL) - mean * mean;
    float r = rsqrtf(var + 1e-5f);
    const float4* g4 = (const float4*)g;
    const float4* b4 = (const float4*)bta;
    unsigned short* orow = out + (size_t)row * D_MODEL;
    #pragma unroll
    for (int j = 0; j < 3; j++) {
        int idx = j * 64 + lane;
        float4 gg = g4[idx], bb = b4[idx];
        u16x4 pk = { f2bf((v[j].x - mean) * r * gg.x + bb.x),
                     f2bf((v[j].y - mean) * r * gg.y + bb.y),
                     f2bf((v[j].z - mean) * r * gg.z + bb.z),
                     f2bf((v[j].w - mean) * r * gg.w + bb.w) };
        *(u16x4*)&orow[idx * 4] = pk;
    }
}

__global__ __launch_bounds__(256) void ln_f32_kernel(const float* __restrict__ x,
                                                     const float* __restrict__ g,
                                                     const float* __restrict__ bta,
                                                     float* __restrict__ out,
                                                     long in_stride, long out_stride) {
    long row = blockIdx.x;
    const float* xr = x + row * in_stride;
    int tid = threadIdx.x;
    float v0 = xr[tid], v1 = xr[tid + 256], v2 = xr[tid + 512];
    float sum = v0 + v1 + v2;
    float sq = v0 * v0 + v1 * v1 + v2 * v2;
    for (int off = 32; off; off >>= 1) {
        sum += __shfl_xor(sum, off);
        sq += __shfl_xor(sq, off);
    }
    __shared__ float red[8];
    int wid = tid >> 6;
    if ((tid & 63) == 0) { red[wid] = sum; red[4 + wid] = sq; }
    __syncthreads();
    sum = red[0] + red[1] + red[2] + red[3];
    sq = red[4] + red[5] + red[6] + red[7];
    float mean = sum * (1.0f / D_MODEL);
    float var = sq * (1.0f / D_MODEL) - mean * mean;
    float r = rsqrtf(var + 1e-5f);
    float* orow = out + row * out_stride;
    orow[tid] = (v0 - mean) * r * g[tid] + bta[tid];
    orow[tid + 256] = (v1 - mean) * r * g[tid + 256] + bta[tid + 256];
    orow[tid + 512] = (v2 - mean) * r * g[tid + 512] + bta[tid + 512];
}

// ---------------------------------------------------------------------------
// Fused per-layer weight conversion
// ---------------------------------------------------------------------------
__device__ __forceinline__ void conv_tile(const float* __restrict__ src,
                                          unsigned short* __restrict__ dst,
                                          int R, int C, int rt, int ct,
                                          int tc, int tr) {
    __shared__ float tile[32][33];
    int r0 = rt * 32, c0 = ct * 32;
    #pragma unroll
    for (int i = 0; i < 32; i += 8)
        tile[tr + i][tc] = src[(size_t)(r0 + tr + i) * C + c0 + tc];
    __syncthreads();
    #pragma unroll
    for (int i = 0; i < 32; i += 8)
        dst[(size_t)(c0 + tr + i) * R + r0 + tc] = f2bf(tile[tc][tr + i]);
}

__global__ __launch_bounds__(256) void wconv_layer(const float* __restrict__ attn_w,
                                                   const float* __restrict__ proj_w,
                                                   const float* __restrict__ fc_w,
                                                   const float* __restrict__ mproj_w,
                                                   unsigned short* __restrict__ attn_wt,
                                                   unsigned short* __restrict__ proj_wt,
                                                   unsigned short* __restrict__ fc_wt,
                                                   unsigned short* __restrict__ mproj_wt) {
    int bid = blockIdx.x;
    const float* src; unsigned short* dst; int R, C, CT, tloc;
    if (bid < 1728)      { src = attn_w;  dst = attn_wt;  R = 768;  C = 2304; CT = 72; tloc = bid; }
    else if (bid < 2304) { src = proj_w;  dst = proj_wt;  R = 768;  C = 768;  CT = 24; tloc = bid - 1728; }
    else if (bid < 4608) { src = fc_w;    dst = fc_wt;    R = 768;  C = 3072; CT = 96; tloc = bid - 2304; }
    else                 { src = mproj_w; dst = mproj_wt; R = 3072; C = 768;  CT = 24; tloc = bid - 4608; }
    int rt = tloc / CT, ct = tloc - rt * CT;
    conv_tile(src, dst, R, C, rt, ct, threadIdx.x, threadIdx.y);
}

__global__ __launch_bounds__(256) void wconv_inject(const float* __restrict__ wh_w,
                                                    const float* __restrict__ ws_w,
                                                    const float* __restrict__ wd_w,
                                                    unsigned short* __restrict__ wh_t,
                                                    unsigned short* __restrict__ ws_t,
                                                    unsigned short* __restrict__ wd_t) {
    int bid = blockIdx.x;
    int sel = bid / 576, tloc = bid - sel * 576;
    const float* src = sel == 0 ? wh_w : (sel == 1 ? ws_w : wd_w);
    unsigned short* dst = sel == 0 ? wh_t : (sel == 1 ? ws_t : wd_t);
    int rt = tloc / 24, ct = tloc - rt * 24;
    conv_tile(src, dst, 768, 768, rt, ct, threadIdx.x, threadIdx.y);
}

// ---------------------------------------------------------------------------
// bf16 MFMA GEMM, 128x128 tile, BK=64, XOR-swizzled LDS (2-way reads)
// ---------------------------------------------------------------------------
#define FLAG_OUTBF16 1
#define FLAG_GELU 2
#define FLAG_RESID 4
#define FLAG_MIRROR 8

__global__ __launch_bounds__(256) void mfma_gemm(const unsigned short* __restrict__ A,
                                                 const unsigned short* __restrict__ Wt,
                                                 const float* __restrict__ bias,
                                                 const float* __restrict__ residual,
                                                 float* __restrict__ Cf,
                                                 unsigned short* __restrict__ Cb,
                                                 unsigned short* __restrict__ Cmir,
                                                 int M, int K, int N, int flags) {
    __shared__ unsigned short As[128 * 64];
    __shared__ unsigned short Bs[128 * 64];
    int tid = threadIdx.x;
    int wave = tid >> 6, lane = tid & 63;
    int quad = lane >> 4, l16 = lane & 15;
    int m0 = blockIdx.x * 128, n0 = blockIdx.y * 128;
    int wm = (wave & 1) * 64, wn = (wave >> 1) * 64;
    f32x4 acc[4][4] = {};

    for (int k0 = 0; k0 < K; k0 += 64) {
        #pragma unroll
        for (int i = 0; i < 4; i++) {
            int chunk = i * 256 + wave * 64 + lane;          // dest slot
            int r = chunk >> 3;
            int cc = (chunk & 7) ^ (r & 7);                  // swizzled source
            async_copy16(&As[(i * 256 + wave * 64) * 8],
                         A + (size_t)(m0 + r) * K + k0 + cc * 8);
            async_copy16(&Bs[(i * 256 + wave * 64) * 8],
                         Wt + (size_t)(n0 + r) * K + k0 + cc * 8);
        }
        __syncthreads();
        #pragma unroll
        for (int sub = 0; sub < 2; sub++) {
            bf16x8 af[4], bfr[4];
            #pragma unroll
            for (int mi = 0; mi < 4; mi++) {
                int R = wm + mi * 16 + l16;
                int slot = (sub * 4 + quad) ^ (R & 7);
                af[mi] = *(const bf16x8*)&As[R * 64 + slot * 8];
            }
            #pragma unroll
            for (int ni = 0; ni < 4; ni++) {
                int R = wn + ni * 16 + l16;
                int slot = (sub * 4 + quad) ^ (R & 7);
                bfr[ni] = *(const bf16x8*)&Bs[R * 64 + slot * 8];
            }
            #pragma unroll
            for (int mi = 0; mi < 4; mi++)
                #pragma unroll
                for (int ni = 0; ni < 4; ni++)
                    acc[mi][ni] = __builtin_amdgcn_mfma_f32_16x16x32_bf16(
                        af[mi], bfr[ni], acc[mi][ni], 0, 0, 0);
        }
        __syncthreads();
    }
    #pragma unroll
    for (int mi = 0; mi < 4; mi++) {
        #pragma unroll
        for (int ni = 0; ni < 4; ni++) {
            int col = n0 + wn + ni * 16 + l16;
            float bv = bias[col];
            #pragma unroll
            for (int r = 0; r < 4; r++) {
                int row = m0 + wm + mi * 16 + quad * 4 + r;
                size_t idx = (size_t)row * N + col;
                float v = acc[mi][ni][r] + bv;
                if (flags & FLAG_RESID) v += residual[idx];
                if (flags & FLAG_GELU) v = gelu_fast(v);
                if (flags & FLAG_OUTBF16) Cb[idx] = f2bf(v);
                else Cf[idx] = v;
                if (flags & FLAG_MIRROR) Cmir[idx] = f2bf(v);
            }
        }
    }
}

// ---------------------------------------------------------------------------
// Flash attention, bf16 MFMA, 64-query tile, 64-key steps.
// qt reversed for load balance; Vt staging conflict-free (key = lane).
// ---------------------------------------------------------------------------
__global__ __launch_bounds__(256) void attn_mfma(const unsigned short* __restrict__ qkv,
                                                 unsigned short* __restrict__ o) {
    int qt = gridDim.x - 1 - blockIdx.x;   // long blocks first
    int hh = blockIdx.y, b = blockIdx.z;
    int tid = threadIdx.x, wave = tid >> 6, lane = tid & 63;
    int quad = lane >> 4, l16 = lane & 15;
    __shared__ unsigned short Qs[64][72];
    __shared__ unsigned short Ks[64][72];
    __shared__ unsigned short Vt[64][72];   // [d][key]
    __shared__ unsigned short Ps[4][16][72];
    const size_t rstride = 3 * D_MODEL;
    int q0 = qt * 64;

    {
        size_t qbase = ((size_t)(b * SEQ + q0)) * rstride + hh * HD;
        #pragma unroll
        for (int i = 0; i < 2; i++) {
            int chunk = i * 256 + tid;
            int r = chunk >> 3, cc = chunk & 7;
            *(uint4*)&Qs[r][cc * 8] =
                *(const uint4*)(qkv + qbase + (size_t)r * rstride + cc * 8);
        }
    }

    float m_r[4] = {-1e30f, -1e30f, -1e30f, -1e30f};
    float l_r[4] = {0.f, 0.f, 0.f, 0.f};
    f32x4 oacc[4] = {};

    for (int kt = 0; kt <= qt; kt++) {
        int kb = kt * 64;
        __syncthreads();
        size_t kbase = ((size_t)(b * SEQ + kb)) * rstride + D_MODEL + hh * HD;
        size_t vbase = ((size_t)(b * SEQ + kb)) * rstride + 2 * D_MODEL + hh * HD;
        #pragma unroll
        for (int i = 0; i < 2; i++) {
            int chunk = i * 256 + tid;
            int r = chunk >> 3, cc = chunk & 7;
            *(uint4*)&Ks[r][cc * 8] =
                *(const uint4*)(qkv + kbase + (size_t)r * rstride + cc * 8);
        }
        // V transpose staging: key = lane (per wave), dg = i*4 + wave
        // write banks: (row*36 + key/2) % 32 -> 2-way only
        #pragma unroll
        for (int i = 0; i < 2; i++) {
            int key = lane;
            int dg = i * 4 + wave;
            uint4 vv = *(const uint4*)(qkv + vbase + (size_t)key * rstride + dg * 8);
            const unsigned short* vs = (const unsigned short*)&vv;
            #pragma unroll
            for (int j = 0; j < 8; j++) Vt[dg * 8 + j][key] = vs[j];
        }
        __syncthreads();

        f32x4 sacc[4] = {};
        bf16x8 qf0 = *(const bf16x8*)&Qs[wave * 16 + l16][quad * 8];
        bf16x8 qf1 = *(const bf16x8*)&Qs[wave * 16 + l16][32 + quad * 8];
        #pragma unroll
        for (int ni = 0; ni < 4; ni++) {
            bf16x8 kf0 = *(const bf16x8*)&Ks[ni * 16 + l16][quad * 8];
            bf16x8 kf1 = *(const bf16x8*)&Ks[ni * 16 + l16][32 + quad * 8];
            sacc[ni] = __builtin_amdgcn_mfma_f32_16x16x32_bf16(qf0, kf0, sacc[ni], 0, 0, 0);
            sacc[ni] = __builtin_amdgcn_mfma_f32_16x16x32_bf16(qf1, kf1, sacc[ni], 0, 0, 0);
        }

        bool diag = (kt == qt);
        const float scale = 0.125f;
        #pragma unroll
        for (int r = 0; r < 4; r++) {
            int qrow_loc = wave * 16 + quad * 4 + r;
            float mx = m_r[r];
            #pragma unroll
            for (int ni = 0; ni < 4; ni++) {
                float sv = sacc[ni][r] * scale;
                if (diag && (ni * 16 + l16 > qrow_loc)) sv = -1e30f;
                sacc[ni][r] = sv;
                mx = fmaxf(mx, sv);
            }
            for (int off = 8; off; off >>= 1) mx = fmaxf(mx, __shfl_xor(mx, off));
            float alpha = __expf(m_r[r] - mx);
            m_r[r] = mx;
            float ls = 0.f;
            #pragma unroll
            for (int ni = 0; ni < 4; ni++) {
                float p = __expf(sacc[ni][r] - mx);
                sacc[ni][r] = p;
                ls += p;
            }
            for (int off = 8; off; off >>= 1) ls += __shfl_xor(ls, off);
            l_r[r] = l_r[r] * alpha + ls;
            #pragma unroll
            for (int ni = 0; ni < 4; ni++) oacc[ni][r] *= alpha;
        }

        #pragma unroll
        for (int ni = 0; ni < 4; ni++)
            #pragma unroll
            for (int r = 0; r < 4; r++)
                Ps[wave][quad * 4 + r][ni * 16 + l16] = f2bf(sacc[ni][r]);
        asm volatile("s_waitcnt lgkmcnt(0)" ::: "memory");

        bf16x8 pf0 = *(const bf16x8*)&Ps[wave][l16][quad * 8];
        bf16x8 pf1 = *(const bf16x8*)&Ps[wave][l16][32 + quad * 8];
        #pragma unroll
        for (int ni = 0; ni < 4; ni++) {
            bf16x8 vf0 = *(const bf16x8*)&Vt[ni * 16 + l16][quad * 8];
            bf16x8 vf1 = *(const bf16x8*)&Vt[ni * 16 + l16][32 + quad * 8];
            oacc[ni] = __builtin_amdgcn_mfma_f32_16x16x32_bf16(pf0, vf0, oacc[ni], 0, 0, 0);
            oacc[ni] = __builtin_amdgcn_mfma_f32_16x16x32_bf16(pf1, vf1, oacc[ni], 0, 0, 0);
        }
    }

    #pragma unroll
    for (int ni = 0; ni < 4; ni++) {
        #pragma unroll
        for (int r = 0; r < 4; r++) {
            float inv = 1.0f / l_r[r];
            int row = q0 + wave * 16 + quad * 4 + r;
            o[((size_t)(b * SEQ + row)) * D_MODEL + hh * HD + ni * 16 + l16] =
                f2bf(oacc[ni][r] * inv);
        }
    }
}

// ---------------------------------------------------------------------------
__global__ __launch_bounds__(256) void gate_kernel(float* __restrict__ h,
                                                   const float* __restrict__ z,
                                                   const float* __restrict__ dv,
                                                   size_t total) {
    size_t i = (size_t)blockIdx.x * blockDim.x + threadIdx.x;
    size_t stride = (size_t)gridDim.x * blockDim.x;
    for (; i < total; i += stride) {
        float g = 1.0f / (1.0f + __expf(-z[i]));
        h[i] += g * dv[i];
    }
}

__global__ __launch_bounds__(64) void head_kernel(const float* __restrict__ hn,
                                                  const float* __restrict__ head_w,
                                                  const float* __restrict__ head_b,
                                                  float* __restrict__ out) {
    int b = blockIdx.x;
    int n = threadIdx.x;
    if (n < NTOK) {
        float acc = head_b[n];
        const float* hr = hn + b * D_MODEL;
        for (int k = 0; k < D_MODEL; k++) acc += hr[k] * head_w[k * NTOK + n];
        out[b * NTOK + n] = acc;
    }
}

// ---------------------------------------------------------------------------
extern "C" void kernel_launch(void* const* d_in, const int* in_sizes, int n_in,
                              void* d_out, int out_size, void* d_ws, size_t ws_size,
                              hipStream_t stream) {
    (void)in_sizes; (void)n_in; (void)out_size; (void)ws_size;
    const int* input_ids = (const int*)d_in[0];
    const int* mul       = (const int*)d_in[1];
    const float* tok_emb = (const float*)d_in[2];
    const float* state_emb = (const float*)d_in[3];
    const float* sp_w = (const float*)d_in[4];
    const float* sp_b = (const float*)d_in[5];
    const float* wh_w = (const float*)d_in[6];
    const float* wh_b = (const float*)d_in[7];
    const float* ws_w = (const float*)d_in[8];
    const float* ws_b = (const float*)d_in[9];
    const float* wd_w = (const float*)d_in[10];
    const float* wd_b = (const float*)d_in[11];
    const float* head_w = (const float*)d_in[12];
    const float* head_b = (const float*)d_in[13];
    const float* wpe  = (const float*)d_in[14];
    const float* ln1_g = (const float*)d_in[15];
    const float* ln1_b = (const float*)d_in[16];
    const float* attn_w = (const float*)d_in[17];
    const float* attn_b = (const float*)d_in[18];
    const float* proj_w = (const float*)d_in[19];
    const float* proj_b = (const float*)d_in[20];
    const float* ln2_g = (const float*)d_in[21];
    const float* ln2_b = (const float*)d_in[22];
    const float* fc_w = (const float*)d_in[23];
    const float* fc_b = (const float*)d_in[24];
    const float* mproj_w = (const float*)d_in[25];
    const float* mproj_b = (const float*)d_in[26];
    const float* lnf_g = (const float*)d_in[27];
    const float* lnf_b = (const float*)d_in[28];
    float* out = (float*)d_out;

    size_t off = 0;
    auto alloc = [&](size_t bytes) {
        void* p = (char*)d_ws + off;
        off += (bytes + 255) & ~(size_t)255;
        return p;
    };
    int* pre = (int*)alloc((size_t)NT * 4);
    float* stable = (float*)alloc((size_t)NTOK * D_MODEL * 4);
    unsigned short* s_bf   = (unsigned short*)alloc((size_t)NT * D_MODEL * 2);
    float* h               = (float*)alloc((size_t)NT * D_MODEL * 4);
    unsigned short* a_bf   = (unsigned short*)alloc((size_t)NT * D_MODEL * 2);
    unsigned short* qkv_bf = (unsigned short*)alloc((size_t)NT * 3 * D_MODEL * 2);
    unsigned short* u_bf   = (unsigned short*)alloc((size_t)NT * 4 * D_MODEL * 2);
    unsigned short* h8_bf  = (unsigned short*)alloc((size_t)NT * D_MODEL * 2);
    float* z  = (float*)alloc((size_t)NT * D_MODEL * 4);
    float* dv = (float*)alloc((size_t)NT * D_MODEL * 4);
    float* hn = (float*)alloc((size_t)BATCH * D_MODEL * 4);
    unsigned short* attn_wt  = (unsigned short*)alloc((size_t)2304 * 768 * 2);
    unsigned short* proj_wt  = (unsigned short*)alloc((size_t)768 * 768 * 2);
    unsigned short* fc_wt    = (unsigned short*)alloc((size_t)3072 * 768 * 2);
    unsigned short* mproj_wt = (unsigned short*)alloc((size_t)768 * 3072 * 2);
    unsigned short* wh_t = (unsigned short*)alloc((size_t)768 * 768 * 2);
    unsigned short* ws_t = (unsigned short*)alloc((size_t)768 * 768 * 2);
    unsigned short* wd_t = (unsigned short*)alloc((size_t)768 * 768 * 2);

    scan_kernel<<<BATCH, 1024, 0, stream>>>(input_ids, mul, pre);
    state_table_kernel<<<NTOK, 256, 0, stream>>>(state_emb, sp_w, sp_b, stable);
    embed_gather<<<NT, 64, 0, stream>>>(input_ids, pre, tok_emb, stable, wpe, s_bf, h);
    wconv_inject<<<1728, dim3(32, 8), 0, stream>>>(wh_w, ws_w, wd_w, wh_t, ws_t, wd_t);

    for (int l = 0; l < L_LAYERS; l++) {
        wconv_layer<<<6912, dim3(32, 8), 0, stream>>>(
            attn_w + (size_t)l * 768 * 2304, proj_w + (size_t)l * 768 * 768,
            fc_w + (size_t)l * 768 * 3072, mproj_w + (size_t)l * 3072 * 768,
            attn_wt, proj_wt, fc_wt, mproj_wt);

        ln_bf16_kernel<<<NT / 4, 256, 0, stream>>>(h, ln1_g + l * D_MODEL,
                                                   ln1_b + l * D_MODEL, a_bf);
        mfma_gemm<<<dim3(NT / 128, 2304 / 128), 256, 0, stream>>>(
            a_bf, attn_wt, attn_b + (size_t)l * 2304, nullptr,
            nullptr, qkv_bf, nullptr, NT, 768, 2304, FLAG_OUTBF16);
        attn_mfma<<<dim3(SEQ / 64, H_HEADS, BATCH), 256, 0, stream>>>(qkv_bf, a_bf);
        mfma_gemm<<<dim3(NT / 128, 768 / 128), 256, 0, stream>>>(
            a_bf, proj_wt, proj_b + (size_t)l * 768, h,
            h, nullptr, nullptr, NT, 768, 768, FLAG_RESID);
        ln_bf16_kernel<<<NT / 4, 256, 0, stream>>>(h, ln2_g + l * D_MODEL,
                                                   ln2_b + l * D_MODEL, a_bf);
        mfma_gemm<<<dim3(NT / 128, 3072 / 128), 256, 0, stream>>>(
            a_bf, fc_wt, fc_b + (size_t)l * 3072, nullptr,
            nullptr, u_bf, nullptr, NT, 768, 3072, FLAG_OUTBF16 | FLAG_GELU);
        int mpflags = FLAG_RESID | (l == INJECT_L ? FLAG_MIRROR : 0);
        mfma_gemm<<<dim3(NT / 128, 768 / 128), 256, 0, stream>>>(
            u_bf, mproj_wt, mproj_b + (size_t)l * 768, h,
            h, nullptr, h8_bf, NT, 3072, 768, mpflags);

        if (l == INJECT_L) {
            mfma_gemm<<<dim3(NT / 128, 768 / 128), 256, 0, stream>>>(
                h8_bf, wh_t, wh_b, nullptr, z, nullptr, nullptr, NT, 768, 768, 0);
            mfma_gemm<<<dim3(NT / 128, 768 / 128), 256, 0, stream>>>(
                s_bf, ws_t, ws_b, z, z, nullptr, nullptr, NT, 768, 768, FLAG_RESID);
            mfma_gemm<<<dim3(NT / 128, 768 / 128), 256, 0, stream>>>(
                s_bf, wd_t, wd_b, nullptr, dv, nullptr, nullptr, NT, 768, 768, 0);
            gate_kernel<<<dim3(2048), 256, 0, stream>>>(h, z, dv, (size_t)NT * D_MODEL);
        }
    }

    ln_f32_kernel<<<BATCH, 256, 0, stream>>>(h + (size_t)(SEQ - 1) * D_MODEL,
                                             lnf_g, lnf_b, hn,
                                             (long)SEQ * D_MODEL, D_MODEL);
    head_kernel<<<BATCH, 64, 0, stream>>>(hn, head_w, head_b, out);
}